// Round 9
// baseline (262.218 us; speedup 1.0000x reference)
//
#include <hip/hip_runtime.h>

#define NROWS 2048
#define MCOLS 2048

// ---- d_ws layout (float offsets) ----
#define OFF_AF 0                        // 2048 x 20 (padded A rows, fluid)
#define OFF_AS (OFF_AF + NROWS * 20)    // 2048 x 20 (solid)
#define OFF_BF (OFF_AS + NROWS * 20)    // 2048 x 18
#define OFF_BS (OFF_BF + NROWS * 18)    // 2048 x 18
#define OFF_WP (OFF_BS + NROWS * 18)    // 504 packed tail weights
#define OFF_CF (OFF_WP + 512)           // int counts, fluid, 2048
#define OFF_CS (OFF_CF + NROWS)         // int counts, solid, 2048
#define OFF_LISTS (OFF_CS + NROWS)      // u16 lists region
#define LF_CAP ((size_t)NROWS * MCOLS)  // capacity of fluid list region in u16

// packed tail-weight layout (within OFF_WP), fluid then solid (+252)
#define WP_W1 0
#define WP_B1 162
#define WP_W2 171
#define WP_B2 225
#define WP_W3 231
#define WP_B3 249
#define WP_SOLID 252

typedef float v2f __attribute__((ext_vector_type(2)));

__device__ __forceinline__ v2f SP(float s) { return (v2f){s, s}; }

// exp2-based tanh: absmax 0.5 verified R1-R8. (Pade 3/3 FAILED in R5.)
__device__ __forceinline__ float fast_tanh(float x) {
    float t = __builtin_amdgcn_exp2f(x * 2.8853900817779268f);
    return 1.0f - 2.0f * __builtin_amdgcn_rcpf(1.0f + t);
}

__device__ __forceinline__ v2f vtanh(v2f x) {
    v2f xs = x * SP(2.8853900817779268f);
    v2f t;
    t.x = __builtin_amdgcn_exp2f(xs.x);
    t.y = __builtin_amdgcn_exp2f(xs.y);
    v2f d = t + SP(1.0f);
    v2f r;
    r.x = __builtin_amdgcn_rcpf(d.x);
    r.y = __builtin_amdgcn_rcpf(d.y);
    return SP(1.0f) - SP(2.0f) * r;
}

// ---- scalar tail eval ----
__device__ __forceinline__ void eval_regs(float4 P0, float4 P1, float4 P2,
                                          float4 P3, float2 P4,
                                          const float* __restrict__ Bq,
                                          const float* __restrict__ W,
                                          float& p0, float& p1, float& p2) {
    float h[18];
    h[0]  = fast_tanh(P0.x + Bq[0]);
    h[1]  = fast_tanh(P0.y + Bq[1]);
    h[2]  = fast_tanh(P0.z + Bq[2]);
    h[3]  = fast_tanh(P0.w + Bq[3]);
    h[4]  = fast_tanh(P1.x + Bq[4]);
    h[5]  = fast_tanh(P1.y + Bq[5]);
    h[6]  = fast_tanh(P1.z + Bq[6]);
    h[7]  = fast_tanh(P1.w + Bq[7]);
    h[8]  = fast_tanh(P2.x + Bq[8]);
    h[9]  = fast_tanh(P2.y + Bq[9]);
    h[10] = fast_tanh(P2.z + Bq[10]);
    h[11] = fast_tanh(P2.w + Bq[11]);
    h[12] = fast_tanh(P3.x + Bq[12]);
    h[13] = fast_tanh(P3.y + Bq[13]);
    h[14] = fast_tanh(P3.z + Bq[14]);
    h[15] = fast_tanh(P3.w + Bq[15]);
    h[16] = fast_tanh(P4.x + Bq[16]);
    h[17] = fast_tanh(P4.y + Bq[17]);
    float g[9];
#pragma unroll
    for (int o = 0; o < 9; ++o) g[o] = W[WP_B1 + o];
#pragma unroll
    for (int j = 0; j < 18; ++j) {
        const float a = h[j];
#pragma unroll
        for (int o = 0; o < 9; ++o) g[o] += a * W[WP_W1 + j * 9 + o];
    }
#pragma unroll
    for (int o = 0; o < 9; ++o) g[o] = fast_tanh(g[o]);
    float q[6];
#pragma unroll
    for (int o = 0; o < 6; ++o) q[o] = W[WP_B2 + o];
#pragma unroll
    for (int j = 0; j < 9; ++j) {
        const float a = g[j];
#pragma unroll
        for (int o = 0; o < 6; ++o) q[o] += a * W[WP_W2 + j * 6 + o];
    }
#pragma unroll
    for (int o = 0; o < 6; ++o) q[o] = fast_tanh(q[o]);
    float o0 = W[WP_B3 + 0], o1 = W[WP_B3 + 1], o2 = W[WP_B3 + 2];
#pragma unroll
    for (int j = 0; j < 6; ++j) {
        const float a = q[j];
        o0 += a * W[WP_W3 + j * 3 + 0];
        o1 += a * W[WP_W3 + j * 3 + 1];
        o2 += a * W[WP_W3 + j * 3 + 2];
    }
    p0 += o0; p1 += o1; p2 += o2;
}

__device__ __forceinline__ void eval_single(const float* __restrict__ A, int m,
                                            const float* __restrict__ Bq,
                                            const float* __restrict__ W,
                                            float& p0, float& p1, float& p2) {
    const float* r = A + m * 20;
    eval_regs(*(const float4*)(r), *(const float4*)(r + 4),
              *(const float4*)(r + 8), *(const float4*)(r + 12),
              *(const float2*)(r + 16), Bq, W, p0, p1, p2);
}

// ---- pk pair eval on pre-loaded registers ----
__device__ __forceinline__ void eval_pair_regs(
        float4 X0, float4 X1, float4 X2, float4 X3, float2 X4,
        float4 Y0, float4 Y1, float4 Y2, float4 Y3, float2 Y4,
        const float* __restrict__ Bq, const float* __restrict__ W,
        v2f& s0, v2f& s1, v2f& s2) {
    v2f h[18];
    h[0]  = vtanh((v2f){X0.x, Y0.x} + SP(Bq[0]));
    h[1]  = vtanh((v2f){X0.y, Y0.y} + SP(Bq[1]));
    h[2]  = vtanh((v2f){X0.z, Y0.z} + SP(Bq[2]));
    h[3]  = vtanh((v2f){X0.w, Y0.w} + SP(Bq[3]));
    h[4]  = vtanh((v2f){X1.x, Y1.x} + SP(Bq[4]));
    h[5]  = vtanh((v2f){X1.y, Y1.y} + SP(Bq[5]));
    h[6]  = vtanh((v2f){X1.z, Y1.z} + SP(Bq[6]));
    h[7]  = vtanh((v2f){X1.w, Y1.w} + SP(Bq[7]));
    h[8]  = vtanh((v2f){X2.x, Y2.x} + SP(Bq[8]));
    h[9]  = vtanh((v2f){X2.y, Y2.y} + SP(Bq[9]));
    h[10] = vtanh((v2f){X2.z, Y2.z} + SP(Bq[10]));
    h[11] = vtanh((v2f){X2.w, Y2.w} + SP(Bq[11]));
    h[12] = vtanh((v2f){X3.x, Y3.x} + SP(Bq[12]));
    h[13] = vtanh((v2f){X3.y, Y3.y} + SP(Bq[13]));
    h[14] = vtanh((v2f){X3.z, Y3.z} + SP(Bq[14]));
    h[15] = vtanh((v2f){X3.w, Y3.w} + SP(Bq[15]));
    h[16] = vtanh((v2f){X4.x, Y4.x} + SP(Bq[16]));
    h[17] = vtanh((v2f){X4.y, Y4.y} + SP(Bq[17]));
    v2f g[9];
#pragma unroll
    for (int o = 0; o < 9; ++o) g[o] = SP(W[WP_B1 + o]);
#pragma unroll
    for (int j = 0; j < 18; ++j) {
        const v2f a = h[j];
#pragma unroll
        for (int o = 0; o < 9; ++o) g[o] += a * SP(W[WP_W1 + j * 9 + o]);
    }
#pragma unroll
    for (int o = 0; o < 9; ++o) g[o] = vtanh(g[o]);
    v2f q[6];
#pragma unroll
    for (int o = 0; o < 6; ++o) q[o] = SP(W[WP_B2 + o]);
#pragma unroll
    for (int j = 0; j < 9; ++j) {
        const v2f a = g[j];
#pragma unroll
        for (int o = 0; o < 6; ++o) q[o] += a * SP(W[WP_W2 + j * 6 + o]);
    }
#pragma unroll
    for (int o = 0; o < 6; ++o) q[o] = vtanh(q[o]);
    v2f o0 = SP(W[WP_B3 + 0]), o1 = SP(W[WP_B3 + 1]), o2 = SP(W[WP_B3 + 2]);
#pragma unroll
    for (int j = 0; j < 6; ++j) {
        const v2f a = q[j];
        o0 += a * SP(W[WP_W3 + j * 3 + 0]);
        o1 += a * SP(W[WP_W3 + j * 3 + 1]);
        o2 += a * SP(W[WP_W3 + j * 3 + 2]);
    }
    s0 += o0; s1 += o1; s2 += o2;
}

// V-exp: pk pair + 2-deep prefetch of both next rows.
__device__ __forceinline__ void row_loop_pair_pipe(const float* __restrict__ A,
                                                   const unsigned short* __restrict__ lst,
                                                   int cnt,
                                                   const float* __restrict__ Bq,
                                                   const float* __restrict__ W,
                                                   int tid,
                                                   v2f& s0, v2f& s1, v2f& s2,
                                                   float& p0, float& p1, float& p2) {
    const unsigned int* l32 = (const unsigned int*)lst;
    const int np = cnt >> 1;
    int i = tid;
    if (i < np) {
        unsigned int mm = l32[i];
        const float* r0 = A + (int)(mm & 0xffffu) * 20;
        const float* r1 = A + (int)(mm >> 16) * 20;
        float4 X0 = *(const float4*)(r0);
        float4 X1 = *(const float4*)(r0 + 4);
        float4 X2 = *(const float4*)(r0 + 8);
        float4 X3 = *(const float4*)(r0 + 12);
        float2 X4 = *(const float2*)(r0 + 16);
        float4 Y0 = *(const float4*)(r1);
        float4 Y1 = *(const float4*)(r1 + 4);
        float4 Y2 = *(const float4*)(r1 + 8);
        float4 Y3 = *(const float4*)(r1 + 12);
        float2 Y4 = *(const float2*)(r1 + 16);
        for (;;) {
            const int inext = i + 256;
            const bool more = inext < np;
            const unsigned int mmn = l32[more ? inext : i];
            const float* n0 = A + (int)(mmn & 0xffffu) * 20;
            const float* n1 = A + (int)(mmn >> 16) * 20;
            const float4 NX0 = *(const float4*)(n0);
            const float4 NX1 = *(const float4*)(n0 + 4);
            const float4 NX2 = *(const float4*)(n0 + 8);
            const float4 NX3 = *(const float4*)(n0 + 12);
            const float2 NX4 = *(const float2*)(n0 + 16);
            const float4 NY0 = *(const float4*)(n1);
            const float4 NY1 = *(const float4*)(n1 + 4);
            const float4 NY2 = *(const float4*)(n1 + 8);
            const float4 NY3 = *(const float4*)(n1 + 12);
            const float2 NY4 = *(const float2*)(n1 + 16);
            eval_pair_regs(X0, X1, X2, X3, X4, Y0, Y1, Y2, Y3, Y4,
                           Bq, W, s0, s1, s2);
            if (!more) break;
            X0 = NX0; X1 = NX1; X2 = NX2; X3 = NX3; X4 = NX4;
            Y0 = NY0; Y1 = NY1; Y2 = NY2; Y3 = NY3; Y4 = NY4;
            i = inext;
        }
    }
    if ((cnt & 1) && tid == 0)
        eval_single(A, lst[cnt - 1], Bq, W, p0, p1, p2);
}

// control: scalar 2-deep pipeline (R6 winner).
__device__ __forceinline__ void row_loop_pipe(const float* __restrict__ A,
                                              const unsigned short* __restrict__ lst,
                                              int cnt,
                                              const float* __restrict__ Bq,
                                              const float* __restrict__ W,
                                              int tid,
                                              float& p0, float& p1, float& p2) {
    int i = tid;
    if (i >= cnt) return;
    const float* r = A + (int)lst[i] * 20;
    float4 P0 = *(const float4*)(r);
    float4 P1 = *(const float4*)(r + 4);
    float4 P2 = *(const float4*)(r + 8);
    float4 P3 = *(const float4*)(r + 12);
    float2 P4 = *(const float2*)(r + 16);
    for (;;) {
        const int inext = i + 256;
        const bool more = inext < cnt;
        const float* rn = A + (int)lst[more ? inext : i] * 20;
        const float4 N0 = *(const float4*)(rn);
        const float4 N1 = *(const float4*)(rn + 4);
        const float4 N2 = *(const float4*)(rn + 8);
        const float4 N3 = *(const float4*)(rn + 12);
        const float2 N4 = *(const float2*)(rn + 16);
        eval_regs(P0, P1, P2, P3, P4, Bq, W, p0, p1, p2);
        if (!more) break;
        P0 = N0; P1 = N1; P2 = N2; P3 = N3; P4 = N4;
        i = inext;
    }
}

__global__ void prep_kernel(const int* __restrict__ index,
                            const float* __restrict__ data,
                            const float* __restrict__ wf0, const float* __restrict__ bf0,
                            const float* __restrict__ sw0, const float* __restrict__ sb0,
                            const float* __restrict__ wf1, const float* __restrict__ bf1,
                            const float* __restrict__ wf2, const float* __restrict__ bf2,
                            const float* __restrict__ wf3, const float* __restrict__ bf3,
                            const float* __restrict__ sw1, const float* __restrict__ sb1,
                            const float* __restrict__ sw2, const float* __restrict__ sb2,
                            const float* __restrict__ sw3, const float* __restrict__ sb3,
                            float* __restrict__ wsp) {
    int i = blockIdx.x * blockDim.x + threadIdx.x;
    if (i < NROWS) {
        float d[7], cen[7];
#pragma unroll
        for (int c = 0; c < 7; ++c) d[c] = data[i * 7 + c];
        int ci = index[i];
#pragma unroll
        for (int c = 0; c < 7; ++c) cen[c] = data[ci * 7 + c];
#pragma unroll
        for (int j = 0; j < 18; ++j) {
            float af = 0.f;
#pragma unroll
            for (int c = 0; c < 7; ++c) af += d[c] * wf0[c * 18 + j];
            float as = d[0] * sw0[0 * 18 + j] + d[1] * sw0[1 * 18 + j] + d[2] * sw0[2 * 18 + j];
            float bf = bf0[j], bs = sb0[j];
#pragma unroll
            for (int c = 0; c < 3; ++c) bf -= cen[c] * wf0[c * 18 + j];
#pragma unroll
            for (int c = 0; c < 4; ++c) bf += cen[3 + c] * wf0[(7 + c) * 18 + j];
#pragma unroll
            for (int c = 0; c < 3; ++c) bs -= cen[c] * sw0[c * 18 + j];
#pragma unroll
            for (int c = 0; c < 4; ++c) bs += cen[3 + c] * sw0[(3 + c) * 18 + j];
            wsp[OFF_AF + i * 20 + j] = af;
            wsp[OFF_AS + i * 20 + j] = as;
            wsp[OFF_BF + i * 18 + j] = bf;
            wsp[OFF_BS + i * 18 + j] = bs;
        }
        wsp[OFF_AF + i * 20 + 18] = 0.f; wsp[OFF_AF + i * 20 + 19] = 0.f;
        wsp[OFF_AS + i * 20 + 18] = 0.f; wsp[OFF_AS + i * 20 + 19] = 0.f;
    }
    if (blockIdx.x == 0) {
        int t = threadIdx.x;
        float* wp = wsp + OFF_WP;
        for (int k = t; k < 162; k += 256) wp[WP_W1 + k] = wf1[k];
        for (int k = t; k < 9;   k += 256) wp[WP_B1 + k] = bf1[k];
        for (int k = t; k < 54;  k += 256) wp[WP_W2 + k] = wf2[k];
        for (int k = t; k < 6;   k += 256) wp[WP_B2 + k] = bf2[k];
        for (int k = t; k < 18;  k += 256) wp[WP_W3 + k] = wf3[k];
        for (int k = t; k < 3;   k += 256) wp[WP_B3 + k] = bf3[k];
        for (int k = t; k < 162; k += 256) wp[WP_SOLID + WP_W1 + k] = sw1[k];
        for (int k = t; k < 9;   k += 256) wp[WP_SOLID + WP_B1 + k] = sb1[k];
        for (int k = t; k < 54;  k += 256) wp[WP_SOLID + WP_W2 + k] = sw2[k];
        for (int k = t; k < 6;   k += 256) wp[WP_SOLID + WP_B2 + k] = sb2[k];
        for (int k = t; k < 18;  k += 256) wp[WP_SOLID + WP_W3 + k] = sw3[k];
        for (int k = t; k < 3;   k += 256) wp[WP_SOLID + WP_B3 + k] = sb3[k];
    }
}

__global__ __launch_bounds__(256)
void compact_kernel(const int* __restrict__ mask,
                    const float* __restrict__ data,
                    float* __restrict__ wsp) {
    const int lane = threadIdx.x & 63;
    const int n = blockIdx.x * 4 + (threadIdx.x >> 6);
    int* counts_f = (int*)(wsp + OFF_CF);
    int* counts_s = (int*)(wsp + OFF_CS);
    unsigned short* lf = (unsigned short*)(wsp + OFF_LISTS) + (size_t)n * MCOLS;
    unsigned short* ls = lf + LF_CAP;
    const int* mrow = mask + (size_t)n * MCOLS;
    int bf = 0, bs = 0;
    const unsigned long long ltmask = (1ull << lane) - 1ull;
#pragma unroll 1
    for (int it = 0; it < MCOLS / 64; ++it) {
        const int m = it * 64 + lane;
        const int mk = mrow[m];
        const float flag = data[m * 7 + 6];
        const bool af = mk && (flag > 0.f);
        const bool as = mk && (flag < 1.f);
        const unsigned long long balf = __ballot(af);
        const unsigned long long bals = __ballot(as);
        if (af) lf[bf + __popcll(balf & ltmask)] = (unsigned short)m;
        if (as) ls[bs + __popcll(bals & ltmask)] = (unsigned short)m;
        bf += __popcll(balf);
        bs += __popcll(bals);
    }
    if (lane == 0) { counts_f[n] = bf; counts_s[n] = bs; }
}

template <int VAR>
__device__ __forceinline__ void main_body(const float* __restrict__ wsp,
                                          float* __restrict__ out) {
    const int n = blockIdx.x;
    const int tid = threadIdx.x;
    __shared__ float red[3][4];
    const float* __restrict__ W  = wsp + OFF_WP;
    const float* __restrict__ Bf = wsp + OFF_BF + n * 18;
    const float* __restrict__ Bs = wsp + OFF_BS + n * 18;
    const int cf = ((const int*)(wsp + OFF_CF))[n];
    const int cs = ((const int*)(wsp + OFF_CS))[n];
    const unsigned short* lf = (const unsigned short*)(wsp + OFF_LISTS) + (size_t)n * MCOLS;
    const unsigned short* ls = lf + LF_CAP;

    float p0 = 0.f, p1 = 0.f, p2 = 0.f;
    if (VAR == 0) {
        row_loop_pipe(wsp + OFF_AF, lf, cf, Bf, W, tid, p0, p1, p2);
        row_loop_pipe(wsp + OFF_AS, ls, cs, Bs, W + WP_SOLID, tid, p0, p1, p2);
    } else {
        v2f s0 = SP(0.f), s1 = SP(0.f), s2 = SP(0.f);
        row_loop_pair_pipe(wsp + OFF_AF, lf, cf, Bf, W, tid, s0, s1, s2, p0, p1, p2);
        row_loop_pair_pipe(wsp + OFF_AS, ls, cs, Bs, W + WP_SOLID, tid, s0, s1, s2, p0, p1, p2);
        p0 += s0.x + s0.y; p1 += s1.x + s1.y; p2 += s2.x + s2.y;
    }

#pragma unroll
    for (int off = 32; off > 0; off >>= 1) {
        p0 += __shfl_xor(p0, off, 64);
        p1 += __shfl_xor(p1, off, 64);
        p2 += __shfl_xor(p2, off, 64);
    }
    const int wid = tid >> 6;
    if ((tid & 63) == 0) { red[0][wid] = p0; red[1][wid] = p1; red[2][wid] = p2; }
    __syncthreads();
    if (tid == 0) {
        float s0 = 0.f, s1 = 0.f, s2 = 0.f;
#pragma unroll
        for (int w = 0; w < 4; ++w) { s0 += red[0][w]; s1 += red[1][w]; s2 += red[2][w]; }
        out[n * 3 + 0] = s0; out[n * 3 + 1] = s1; out[n * 3 + 2] = s2;
    }
}

// R9: experiments FIRST, known-good control LAST (its output is validated).
__global__ __launch_bounds__(256, 4)
void main_pair_pipe(const float* __restrict__ wsp, float* __restrict__ out) {
    main_body<1>(wsp, out);
}

__global__ __launch_bounds__(256, 6)
void main_pipe6(const float* __restrict__ wsp, float* __restrict__ out) {
    main_body<0>(wsp, out);
}

__global__ __launch_bounds__(256, 4)
void main_pipe4(const float* __restrict__ wsp, float* __restrict__ out) {
    main_body<0>(wsp, out);
}

extern "C" void kernel_launch(void* const* d_in, const int* in_sizes, int n_in,
                              void* d_out, int out_size, void* d_ws, size_t ws_size,
                              hipStream_t stream) {
    const int*   mask  = (const int*)d_in[0];
    const int*   index = (const int*)d_in[1];
    const float* data  = (const float*)d_in[2];
    const float* wf0   = (const float*)d_in[3];
    const float* bf0   = (const float*)d_in[4];
    const float* wf1   = (const float*)d_in[5];
    const float* bf1   = (const float*)d_in[6];
    const float* wf2   = (const float*)d_in[7];
    const float* bf2   = (const float*)d_in[8];
    const float* wf3   = (const float*)d_in[9];
    const float* bf3   = (const float*)d_in[10];
    const float* sw0   = (const float*)d_in[11];
    const float* sb0   = (const float*)d_in[12];
    const float* sw1   = (const float*)d_in[13];
    const float* sb1   = (const float*)d_in[14];
    const float* sw2   = (const float*)d_in[15];
    const float* sb2   = (const float*)d_in[16];
    const float* sw3   = (const float*)d_in[17];
    const float* sb3   = (const float*)d_in[18];
    float* wsp = (float*)d_ws;
    float* out = (float*)d_out;

    prep_kernel<<<dim3(8), dim3(256), 0, stream>>>(
        index, data, wf0, bf0, sw0, sb0, wf1, bf1, wf2, bf2, wf3, bf3,
        sw1, sb1, sw2, sb2, sw3, sb3, wsp);
    compact_kernel<<<dim3(NROWS / 4), dim3(256), 0, stream>>>(mask, data, wsp);
    main_pair_pipe<<<dim3(NROWS), dim3(256), 0, stream>>>(wsp, out);
    main_pipe6<<<dim3(NROWS), dim3(256), 0, stream>>>(wsp, out);
    main_pipe4<<<dim3(NROWS), dim3(256), 0, stream>>>(wsp, out);
}

// Round 10
// 252.624 us; speedup vs baseline: 1.0380x; 1.0380x over previous
//
#include <hip/hip_runtime.h>

#define NROWS 2048
#define MCOLS 2048

// ---- d_ws layout (float offsets); A/B rows padded to stride 20 ----
#define OFF_AF 0                         // 2048 x 20  ([19] = fluid indicator)
#define OFF_AS (OFF_AF + NROWS * 20)     // 2048 x 20  ([19] = solid indicator)
#define OFF_BF (OFF_AS + NROWS * 20)     // 2048 x 20
#define OFF_BS (OFF_BF + NROWS * 20)     // 2048 x 20
#define OFF_WP (OFF_BS + NROWS * 20)     // 504 packed tail weights
#define OFF_CF (OFF_WP + 512)
#define OFF_CS (OFF_CF + NROWS)
#define OFF_LISTS (OFF_CS + NROWS)
#define LF_CAP ((size_t)NROWS * MCOLS)

#define WP_W1 0
#define WP_B1 162
#define WP_W2 171
#define WP_B2 225
#define WP_W3 231
#define WP_B3 249
#define WP_SOLID 252

__device__ __forceinline__ float fast_tanh(float x) {
    float t = __builtin_amdgcn_exp2f(x * 2.8853900817779268f);
    return 1.0f - 2.0f * __builtin_amdgcn_rcpf(1.0f + t);
}

// shared tail on h[18] already computed
__device__ __forceinline__ void tail18(const float* __restrict__ h,
                                       const float* __restrict__ W,
                                       float& o0, float& o1, float& o2) {
    float g[9];
#pragma unroll
    for (int o = 0; o < 9; ++o) g[o] = W[WP_B1 + o];
#pragma unroll
    for (int j = 0; j < 18; ++j) {
        const float a = h[j];
#pragma unroll
        for (int o = 0; o < 9; ++o) g[o] += a * W[WP_W1 + j * 9 + o];
    }
#pragma unroll
    for (int o = 0; o < 9; ++o) g[o] = fast_tanh(g[o]);
    float q[6];
#pragma unroll
    for (int o = 0; o < 6; ++o) q[o] = W[WP_B2 + o];
#pragma unroll
    for (int j = 0; j < 9; ++j) {
        const float a = g[j];
#pragma unroll
        for (int o = 0; o < 6; ++o) q[o] += a * W[WP_W2 + j * 6 + o];
    }
#pragma unroll
    for (int o = 0; o < 6; ++o) q[o] = fast_tanh(q[o]);
    o0 = W[WP_B3 + 0]; o1 = W[WP_B3 + 1]; o2 = W[WP_B3 + 2];
#pragma unroll
    for (int j = 0; j < 6; ++j) {
        const float a = q[j];
        o0 += a * W[WP_W3 + j * 3 + 0];
        o1 += a * W[WP_W3 + j * 3 + 1];
        o2 += a * W[WP_W3 + j * 3 + 2];
    }
}

// control path: A in regs, B via pointer
__device__ __forceinline__ void eval_regs(float4 P0, float4 P1, float4 P2,
                                          float4 P3, float2 P4,
                                          const float* __restrict__ Bq,
                                          const float* __restrict__ W,
                                          float& p0, float& p1, float& p2) {
    float h[18];
    h[0]  = fast_tanh(P0.x + Bq[0]);  h[1]  = fast_tanh(P0.y + Bq[1]);
    h[2]  = fast_tanh(P0.z + Bq[2]);  h[3]  = fast_tanh(P0.w + Bq[3]);
    h[4]  = fast_tanh(P1.x + Bq[4]);  h[5]  = fast_tanh(P1.y + Bq[5]);
    h[6]  = fast_tanh(P1.z + Bq[6]);  h[7]  = fast_tanh(P1.w + Bq[7]);
    h[8]  = fast_tanh(P2.x + Bq[8]);  h[9]  = fast_tanh(P2.y + Bq[9]);
    h[10] = fast_tanh(P2.z + Bq[10]); h[11] = fast_tanh(P2.w + Bq[11]);
    h[12] = fast_tanh(P3.x + Bq[12]); h[13] = fast_tanh(P3.y + Bq[13]);
    h[14] = fast_tanh(P3.z + Bq[14]); h[15] = fast_tanh(P3.w + Bq[15]);
    h[16] = fast_tanh(P4.x + Bq[16]); h[17] = fast_tanh(P4.y + Bq[17]);
    float o0, o1, o2;
    tail18(h, W, o0, o1, o2);
    p0 += o0; p1 += o1; p2 += o2;
}

// ABLATION: identical math shape, but weight indices masked &15 -> 16 uniform
// addresses the compiler hoists into SGPRs (zero in-loop s_loads). Results are
// WRONG on purpose; this kernel's output is overwritten by the control.
__device__ __forceinline__ void eval_regs_lw(float4 P0, float4 P1, float4 P2,
                                             float4 P3, float2 P4,
                                             const float* __restrict__ Bq,
                                             const float* __restrict__ W,
                                             float& p0, float& p1, float& p2) {
    float h[18];
    h[0]  = fast_tanh(P0.x + Bq[0]);  h[1]  = fast_tanh(P0.y + Bq[1]);
    h[2]  = fast_tanh(P0.z + Bq[2]);  h[3]  = fast_tanh(P0.w + Bq[3]);
    h[4]  = fast_tanh(P1.x + Bq[4]);  h[5]  = fast_tanh(P1.y + Bq[5]);
    h[6]  = fast_tanh(P1.z + Bq[6]);  h[7]  = fast_tanh(P1.w + Bq[7]);
    h[8]  = fast_tanh(P2.x + Bq[8]);  h[9]  = fast_tanh(P2.y + Bq[9]);
    h[10] = fast_tanh(P2.z + Bq[10]); h[11] = fast_tanh(P2.w + Bq[11]);
    h[12] = fast_tanh(P3.x + Bq[12]); h[13] = fast_tanh(P3.y + Bq[13]);
    h[14] = fast_tanh(P4.x + Bq[14]); h[15] = fast_tanh(P4.y + Bq[15]);
    h[16] = fast_tanh(P3.z + Bq[16]); h[17] = fast_tanh(P3.w + Bq[17]);
    float g[9];
#pragma unroll
    for (int o = 0; o < 9; ++o) g[o] = W[(WP_B1 + o) & 15];
#pragma unroll
    for (int j = 0; j < 18; ++j) {
        const float a = h[j];
#pragma unroll
        for (int o = 0; o < 9; ++o) g[o] += a * W[(WP_W1 + j * 9 + o) & 15];
    }
#pragma unroll
    for (int o = 0; o < 9; ++o) g[o] = fast_tanh(g[o]);
    float q[6];
#pragma unroll
    for (int o = 0; o < 6; ++o) q[o] = W[(WP_B2 + o) & 15];
#pragma unroll
    for (int j = 0; j < 9; ++j) {
        const float a = g[j];
#pragma unroll
        for (int o = 0; o < 6; ++o) q[o] += a * W[(WP_W2 + j * 6 + o) & 15];
    }
#pragma unroll
    for (int o = 0; o < 6; ++o) q[o] = fast_tanh(q[o]);
    float o0 = W[(WP_B3 + 0) & 15], o1 = W[(WP_B3 + 1) & 15], o2 = W[(WP_B3 + 2) & 15];
#pragma unroll
    for (int j = 0; j < 6; ++j) {
        const float a = q[j];
        o0 += a * W[(WP_W3 + j * 3 + 0) & 15];
        o1 += a * W[(WP_W3 + j * 3 + 1) & 15];
        o2 += a * W[(WP_W3 + j * 3 + 2) & 15];
    }
    p0 += o0; p1 += o1; p2 += o2;
}

// tile path: A and B both in regs
__device__ __forceinline__ void eval_ab(float4 A0, float4 A1, float4 A2,
                                        float4 A3, float2 A4,
                                        float4 B0, float4 B1, float4 B2,
                                        float4 B3, float2 B4,
                                        const float* __restrict__ W,
                                        float& o0, float& o1, float& o2) {
    float h[18];
    h[0]  = fast_tanh(A0.x + B0.x);  h[1]  = fast_tanh(A0.y + B0.y);
    h[2]  = fast_tanh(A0.z + B0.z);  h[3]  = fast_tanh(A0.w + B0.w);
    h[4]  = fast_tanh(A1.x + B1.x);  h[5]  = fast_tanh(A1.y + B1.y);
    h[6]  = fast_tanh(A1.z + B1.z);  h[7]  = fast_tanh(A1.w + B1.w);
    h[8]  = fast_tanh(A2.x + B2.x);  h[9]  = fast_tanh(A2.y + B2.y);
    h[10] = fast_tanh(A2.z + B2.z);  h[11] = fast_tanh(A2.w + B2.w);
    h[12] = fast_tanh(A3.x + B3.x);  h[13] = fast_tanh(A3.y + B3.y);
    h[14] = fast_tanh(A3.z + B3.z);  h[15] = fast_tanh(A3.w + B3.w);
    h[16] = fast_tanh(A4.x + B4.x);  h[17] = fast_tanh(A4.y + B4.y);
    tail18(h, W, o0, o1, o2);
}

__global__ void prep_kernel(const int* __restrict__ index,
                            const float* __restrict__ data,
                            const float* __restrict__ wf0, const float* __restrict__ bf0,
                            const float* __restrict__ sw0, const float* __restrict__ sb0,
                            const float* __restrict__ wf1, const float* __restrict__ bf1,
                            const float* __restrict__ wf2, const float* __restrict__ bf2,
                            const float* __restrict__ wf3, const float* __restrict__ bf3,
                            const float* __restrict__ sw1, const float* __restrict__ sb1,
                            const float* __restrict__ sw2, const float* __restrict__ sb2,
                            const float* __restrict__ sw3, const float* __restrict__ sb3,
                            float* __restrict__ wsp) {
    int i = blockIdx.x * blockDim.x + threadIdx.x;
    if (i < NROWS) {
        float d[7], cen[7];
#pragma unroll
        for (int c = 0; c < 7; ++c) d[c] = data[i * 7 + c];
        int ci = index[i];
#pragma unroll
        for (int c = 0; c < 7; ++c) cen[c] = data[ci * 7 + c];
#pragma unroll
        for (int j = 0; j < 18; ++j) {
            float af = 0.f;
#pragma unroll
            for (int c = 0; c < 7; ++c) af += d[c] * wf0[c * 18 + j];
            float as = d[0] * sw0[0 * 18 + j] + d[1] * sw0[1 * 18 + j] + d[2] * sw0[2 * 18 + j];
            float bf = bf0[j], bs = sb0[j];
#pragma unroll
            for (int c = 0; c < 3; ++c) bf -= cen[c] * wf0[c * 18 + j];
#pragma unroll
            for (int c = 0; c < 4; ++c) bf += cen[3 + c] * wf0[(7 + c) * 18 + j];
#pragma unroll
            for (int c = 0; c < 3; ++c) bs -= cen[c] * sw0[c * 18 + j];
#pragma unroll
            for (int c = 0; c < 4; ++c) bs += cen[3 + c] * sw0[(3 + c) * 18 + j];
            wsp[OFF_AF + i * 20 + j] = af;
            wsp[OFF_AS + i * 20 + j] = as;
            wsp[OFF_BF + i * 20 + j] = bf;
            wsp[OFF_BS + i * 20 + j] = bs;
        }
        wsp[OFF_AF + i * 20 + 18] = 0.f;
        wsp[OFF_AF + i * 20 + 19] = (d[6] > 0.f) ? 1.f : 0.f;
        wsp[OFF_AS + i * 20 + 18] = 0.f;
        wsp[OFF_AS + i * 20 + 19] = (d[6] < 1.f) ? 1.f : 0.f;
        wsp[OFF_BF + i * 20 + 18] = 0.f; wsp[OFF_BF + i * 20 + 19] = 0.f;
        wsp[OFF_BS + i * 20 + 18] = 0.f; wsp[OFF_BS + i * 20 + 19] = 0.f;
    }
    if (blockIdx.x == 0) {
        int t = threadIdx.x;
        float* wp = wsp + OFF_WP;
        for (int k = t; k < 162; k += 256) wp[WP_W1 + k] = wf1[k];
        for (int k = t; k < 9;   k += 256) wp[WP_B1 + k] = bf1[k];
        for (int k = t; k < 54;  k += 256) wp[WP_W2 + k] = wf2[k];
        for (int k = t; k < 6;   k += 256) wp[WP_B2 + k] = bf2[k];
        for (int k = t; k < 18;  k += 256) wp[WP_W3 + k] = wf3[k];
        for (int k = t; k < 3;   k += 256) wp[WP_B3 + k] = bf3[k];
        for (int k = t; k < 162; k += 256) wp[WP_SOLID + WP_W1 + k] = sw1[k];
        for (int k = t; k < 9;   k += 256) wp[WP_SOLID + WP_B1 + k] = sb1[k];
        for (int k = t; k < 54;  k += 256) wp[WP_SOLID + WP_W2 + k] = sw2[k];
        for (int k = t; k < 6;   k += 256) wp[WP_SOLID + WP_B2 + k] = sb2[k];
        for (int k = t; k < 18;  k += 256) wp[WP_SOLID + WP_W3 + k] = sw3[k];
        for (int k = t; k < 3;   k += 256) wp[WP_SOLID + WP_B3 + k] = sb3[k];
    }
}

__global__ __launch_bounds__(256)
void compact_kernel(const int* __restrict__ mask,
                    const float* __restrict__ data,
                    float* __restrict__ wsp) {
    const int lane = threadIdx.x & 63;
    const int n = blockIdx.x * 4 + (threadIdx.x >> 6);
    int* counts_f = (int*)(wsp + OFF_CF);
    int* counts_s = (int*)(wsp + OFF_CS);
    unsigned short* lf = (unsigned short*)(wsp + OFF_LISTS) + (size_t)n * MCOLS;
    unsigned short* ls = lf + LF_CAP;
    const int* mrow = mask + (size_t)n * MCOLS;
    int bf = 0, bs = 0;
    const unsigned long long ltmask = (1ull << lane) - 1ull;
#pragma unroll 1
    for (int it = 0; it < MCOLS / 64; ++it) {
        const int m = it * 64 + lane;
        const int mk = mrow[m];
        const float flag = data[m * 7 + 6];
        const bool af = mk && (flag > 0.f);
        const bool as = mk && (flag < 1.f);
        const unsigned long long balf = __ballot(af);
        const unsigned long long bals = __ballot(as);
        if (af) lf[bf + __popcll(balf & ltmask)] = (unsigned short)m;
        if (as) ls[bs + __popcll(bals & ltmask)] = (unsigned short)m;
        bf += __popcll(balf);
        bs += __popcll(bals);
    }
    if (lane == 0) { counts_f[n] = bf; counts_s[n] = bs; }
}

// ---------- EXPERIMENT: 64x64 LDS-tiled, per-tile compaction ----------
__global__ __launch_bounds__(256, 4)
void main_tile(const int* __restrict__ mask,
               const float* __restrict__ wsp,
               float* __restrict__ out) {
    __shared__ float sAf[64 * 20];
    __shared__ float sAs[64 * 20];
    __shared__ float sBf[64 * 20];
    __shared__ float sBs[64 * 20];
    __shared__ unsigned short pf[4096];
    __shared__ unsigned short ps[4096];
    __shared__ int cnts[2];
    __shared__ float sOut[192];
    const int tid = threadIdx.x;
    const int m0 = blockIdx.x * 64;
    const int n0 = blockIdx.y * 64;
    const float* __restrict__ W = wsp + OFF_WP;

    for (int idx = tid; idx < 1280; idx += 256) {
        sAf[idx] = wsp[OFF_AF + m0 * 20 + idx];
        sAs[idx] = wsp[OFF_AS + m0 * 20 + idx];
        sBf[idx] = wsp[OFF_BF + n0 * 20 + idx];
        sBs[idx] = wsp[OFF_BS + n0 * 20 + idx];
    }
    if (tid < 2) cnts[tid] = 0;
    if (tid < 192) sOut[tid] = 0.f;
    __syncthreads();

    const int lane = tid & 63;
    const unsigned long long lt = (1ull << lane) - 1ull;
#pragma unroll 1
    for (int c = 0; c < 16; ++c) {
        const int p = c * 256 + tid;
        const int nl = p >> 6, ml = p & 63;
        const int mk = mask[(size_t)(n0 + nl) * MCOLS + m0 + ml];
        const bool isf = mk && (sAf[ml * 20 + 19] > 0.5f);
        const bool iss = mk && (sAs[ml * 20 + 19] > 0.5f);
        const unsigned long long bf_ = __ballot(isf);
        const unsigned long long bs_ = __ballot(iss);
        int baseF = 0, baseS = 0;
        if (lane == 0) {
            baseF = atomicAdd(&cnts[0], __popcll(bf_));
            baseS = atomicAdd(&cnts[1], __popcll(bs_));
        }
        baseF = __shfl(baseF, 0, 64);
        baseS = __shfl(baseS, 0, 64);
        if (isf) pf[baseF + __popcll(bf_ & lt)] = (unsigned short)p;
        if (iss) ps[baseS + __popcll(bs_ & lt)] = (unsigned short)p;
    }
    __syncthreads();
    const int cf = cnts[0];
    const int cs = cnts[1];

#pragma unroll 1
    for (int pass = 0; pass < 2; ++pass) {
        const unsigned short* list = pass ? ps : pf;
        const float* sA = pass ? sAs : sAf;
        const float* sB = pass ? sBs : sBf;
        const float* Wp = pass ? (W + WP_SOLID) : W;
        const int cnt = pass ? cs : cf;
        const int len = (cnt + 255) >> 8;
        const int i0 = tid * len;
        const int i1 = min(i0 + len, cnt);
        int curn = -1;
        float a0 = 0.f, a1 = 0.f, a2 = 0.f;
        float4 B0, B1, B2, B3; float2 B4;
#pragma unroll 1
        for (int i = i0; i < i1; ++i) {
            const int p = list[i];
            const int nl = p >> 6, ml = p & 63;
            if (nl != curn) {
                if (curn >= 0) {
                    atomicAdd(&sOut[curn * 3 + 0], a0);
                    atomicAdd(&sOut[curn * 3 + 1], a1);
                    atomicAdd(&sOut[curn * 3 + 2], a2);
                }
                curn = nl; a0 = a1 = a2 = 0.f;
                const float* b = sB + nl * 20;
                B0 = *(const float4*)(b);
                B1 = *(const float4*)(b + 4);
                B2 = *(const float4*)(b + 8);
                B3 = *(const float4*)(b + 12);
                B4 = *(const float2*)(b + 16);
            }
            const float* a = sA + ml * 20;
            const float4 A0 = *(const float4*)(a);
            const float4 A1 = *(const float4*)(a + 4);
            const float4 A2 = *(const float4*)(a + 8);
            const float4 A3 = *(const float4*)(a + 12);
            const float2 A4 = *(const float2*)(a + 16);
            float o0, o1, o2;
            eval_ab(A0, A1, A2, A3, A4, B0, B1, B2, B3, B4, Wp, o0, o1, o2);
            a0 += o0; a1 += o1; a2 += o2;
        }
        if (curn >= 0) {
            atomicAdd(&sOut[curn * 3 + 0], a0);
            atomicAdd(&sOut[curn * 3 + 1], a1);
            atomicAdd(&sOut[curn * 3 + 2], a2);
        }
    }
    __syncthreads();
    if (tid < 192) atomicAdd(&out[n0 * 3 + tid], sOut[tid]);
}

// ---------- control / ablation bodies over per-n lists ----------
template <int LW>
__device__ __forceinline__ void row_loop_pipe(const float* __restrict__ A,
                                              const unsigned short* __restrict__ lst,
                                              int cnt,
                                              const float* __restrict__ Bq,
                                              const float* __restrict__ W,
                                              int tid,
                                              float& p0, float& p1, float& p2) {
    int i = tid;
    if (i >= cnt) return;
    const float* r = A + (int)lst[i] * 20;
    float4 P0 = *(const float4*)(r);
    float4 P1 = *(const float4*)(r + 4);
    float4 P2 = *(const float4*)(r + 8);
    float4 P3 = *(const float4*)(r + 12);
    float2 P4 = *(const float2*)(r + 16);
    for (;;) {
        const int inext = i + 256;
        const bool more = inext < cnt;
        const float* rn = A + (int)lst[more ? inext : i] * 20;
        const float4 N0 = *(const float4*)(rn);
        const float4 N1 = *(const float4*)(rn + 4);
        const float4 N2 = *(const float4*)(rn + 8);
        const float4 N3 = *(const float4*)(rn + 12);
        const float2 N4 = *(const float2*)(rn + 16);
        if (LW) eval_regs_lw(P0, P1, P2, P3, P4, Bq, W, p0, p1, p2);
        else    eval_regs(P0, P1, P2, P3, P4, Bq, W, p0, p1, p2);
        if (!more) break;
        P0 = N0; P1 = N1; P2 = N2; P3 = N3; P4 = N4;
        i = inext;
    }
}

template <int LW>
__device__ __forceinline__ void main_body(const float* __restrict__ wsp,
                                          float* __restrict__ out) {
    const int n = blockIdx.x;
    const int tid = threadIdx.x;
    __shared__ float red[3][4];
    const float* __restrict__ W  = wsp + OFF_WP;
    const float* __restrict__ Bf = wsp + OFF_BF + n * 20;
    const float* __restrict__ Bs = wsp + OFF_BS + n * 20;
    const int cf = ((const int*)(wsp + OFF_CF))[n];
    const int cs = ((const int*)(wsp + OFF_CS))[n];
    const unsigned short* lf = (const unsigned short*)(wsp + OFF_LISTS) + (size_t)n * MCOLS;
    const unsigned short* ls = lf + LF_CAP;

    float p0 = 0.f, p1 = 0.f, p2 = 0.f;
    row_loop_pipe<LW>(wsp + OFF_AF, lf, cf, Bf, W, tid, p0, p1, p2);
    row_loop_pipe<LW>(wsp + OFF_AS, ls, cs, Bs, W + WP_SOLID, tid, p0, p1, p2);

#pragma unroll
    for (int off = 32; off > 0; off >>= 1) {
        p0 += __shfl_xor(p0, off, 64);
        p1 += __shfl_xor(p1, off, 64);
        p2 += __shfl_xor(p2, off, 64);
    }
    const int wid = tid >> 6;
    if ((tid & 63) == 0) { red[0][wid] = p0; red[1][wid] = p1; red[2][wid] = p2; }
    __syncthreads();
    if (tid == 0) {
        float s0 = 0.f, s1 = 0.f, s2 = 0.f;
#pragma unroll
        for (int w = 0; w < 4; ++w) { s0 += red[0][w]; s1 += red[1][w]; s2 += red[2][w]; }
        out[n * 3 + 0] = s0; out[n * 3 + 1] = s1; out[n * 3 + 2] = s2;
    }
}

__global__ __launch_bounds__(256, 4)
void main_lw(const float* __restrict__ wsp, float* __restrict__ out) {
    main_body<1>(wsp, out);
}

__global__ __launch_bounds__(256, 4)
void main_pipe4(const float* __restrict__ wsp, float* __restrict__ out) {
    main_body<0>(wsp, out);
}

extern "C" void kernel_launch(void* const* d_in, const int* in_sizes, int n_in,
                              void* d_out, int out_size, void* d_ws, size_t ws_size,
                              hipStream_t stream) {
    const int*   mask  = (const int*)d_in[0];
    const int*   index = (const int*)d_in[1];
    const float* data  = (const float*)d_in[2];
    const float* wf0   = (const float*)d_in[3];
    const float* bf0   = (const float*)d_in[4];
    const float* wf1   = (const float*)d_in[5];
    const float* bf1   = (const float*)d_in[6];
    const float* wf2   = (const float*)d_in[7];
    const float* bf2   = (const float*)d_in[8];
    const float* wf3   = (const float*)d_in[9];
    const float* bf3   = (const float*)d_in[10];
    const float* sw0   = (const float*)d_in[11];
    const float* sb0   = (const float*)d_in[12];
    const float* sw1   = (const float*)d_in[13];
    const float* sb1   = (const float*)d_in[14];
    const float* sw2   = (const float*)d_in[15];
    const float* sb2   = (const float*)d_in[16];
    const float* sw3   = (const float*)d_in[17];
    const float* sb3   = (const float*)d_in[18];
    float* wsp = (float*)d_ws;
    float* out = (float*)d_out;

    hipMemsetAsync(d_out, 0, (size_t)out_size * sizeof(float), stream);
    prep_kernel<<<dim3(8), dim3(256), 0, stream>>>(
        index, data, wf0, bf0, sw0, sb0, wf1, bf1, wf2, bf2, wf3, bf3,
        sw1, sb1, sw2, sb2, sw3, sb3, wsp);
    compact_kernel<<<dim3(NROWS / 4), dim3(256), 0, stream>>>(mask, data, wsp);
    main_tile<<<dim3(32, 32), dim3(256), 0, stream>>>(mask, wsp, out);
    main_lw<<<dim3(NROWS), dim3(256), 0, stream>>>(wsp, out);
    main_pipe4<<<dim3(NROWS), dim3(256), 0, stream>>>(wsp, out);
}

// Round 11
// 147.178 us; speedup vs baseline: 1.7816x; 1.7165x over previous
//
#include <hip/hip_runtime.h>

#define NROWS 2048
#define MCOLS 2048

// ---- d_ws layout (float offsets); rows padded to stride 20 ----
#define OFF_AF 0
#define OFF_AS (OFF_AF + NROWS * 20)
#define OFF_BF (OFF_AS + NROWS * 20)
#define OFF_BS (OFF_BF + NROWS * 20)
#define OFF_WP (OFF_BS + NROWS * 20)
#define OFF_CF (OFF_WP + 512)
#define OFF_CS (OFF_CF + NROWS)
#define OFF_LISTS (OFF_CS + NROWS)
#define LF_CAP ((size_t)NROWS * MCOLS)

#define WP_W1 0
#define WP_B1 162
#define WP_W2 171
#define WP_B2 225
#define WP_W3 231
#define WP_B3 249
#define WP_SOLID 252

__device__ __forceinline__ float fast_tanh(float x) {
    float t = __builtin_amdgcn_exp2f(x * 2.8853900817779268f);
    return 1.0f - 2.0f * __builtin_amdgcn_rcpf(1.0f + t);
}

// ---------- control eval (R6 winner form) ----------
__device__ __forceinline__ void eval_regs(float4 P0, float4 P1, float4 P2,
                                          float4 P3, float2 P4,
                                          const float* __restrict__ Bq,
                                          const float* __restrict__ W,
                                          float& p0, float& p1, float& p2) {
    float h[18];
    h[0]  = fast_tanh(P0.x + Bq[0]);  h[1]  = fast_tanh(P0.y + Bq[1]);
    h[2]  = fast_tanh(P0.z + Bq[2]);  h[3]  = fast_tanh(P0.w + Bq[3]);
    h[4]  = fast_tanh(P1.x + Bq[4]);  h[5]  = fast_tanh(P1.y + Bq[5]);
    h[6]  = fast_tanh(P1.z + Bq[6]);  h[7]  = fast_tanh(P1.w + Bq[7]);
    h[8]  = fast_tanh(P2.x + Bq[8]);  h[9]  = fast_tanh(P2.y + Bq[9]);
    h[10] = fast_tanh(P2.z + Bq[10]); h[11] = fast_tanh(P2.w + Bq[11]);
    h[12] = fast_tanh(P3.x + Bq[12]); h[13] = fast_tanh(P3.y + Bq[13]);
    h[14] = fast_tanh(P3.z + Bq[14]); h[15] = fast_tanh(P3.w + Bq[15]);
    h[16] = fast_tanh(P4.x + Bq[16]); h[17] = fast_tanh(P4.y + Bq[17]);
    float g[9];
#pragma unroll
    for (int o = 0; o < 9; ++o) g[o] = W[WP_B1 + o];
#pragma unroll
    for (int j = 0; j < 18; ++j) {
        const float a = h[j];
#pragma unroll
        for (int o = 0; o < 9; ++o) g[o] += a * W[WP_W1 + j * 9 + o];
    }
#pragma unroll
    for (int o = 0; o < 9; ++o) g[o] = fast_tanh(g[o]);
    float q[6];
#pragma unroll
    for (int o = 0; o < 6; ++o) q[o] = W[WP_B2 + o];
#pragma unroll
    for (int j = 0; j < 9; ++j) {
        const float a = g[j];
#pragma unroll
        for (int o = 0; o < 6; ++o) q[o] += a * W[WP_W2 + j * 6 + o];
    }
#pragma unroll
    for (int o = 0; o < 6; ++o) q[o] = fast_tanh(q[o]);
    float o0 = W[WP_B3 + 0], o1 = W[WP_B3 + 1], o2 = W[WP_B3 + 2];
#pragma unroll
    for (int j = 0; j < 6; ++j) {
        const float a = q[j];
        o0 += a * W[WP_W3 + j * 3 + 0];
        o1 += a * W[WP_W3 + j * 3 + 1];
        o2 += a * W[WP_W3 + j * 3 + 2];
    }
    p0 += o0; p1 += o1; p2 += o2;
}

// ---------- EXPERIMENT eval: layer-ILP fences ----------
// asm keep-alive after each activation layer forces ALL its values
// simultaneously live -> compiler cannot re-serialize to save VGPRs ->
// the 18 (then 9, 6) independent tanh chains overlap.
__device__ __forceinline__ void eval_regs_ilp(float4 P0, float4 P1, float4 P2,
                                              float4 P3, float2 P4,
                                              const float* __restrict__ Bq,
                                              const float* __restrict__ W,
                                              float& p0, float& p1, float& p2) {
    float h[18];
    h[0]  = fast_tanh(P0.x + Bq[0]);  h[1]  = fast_tanh(P0.y + Bq[1]);
    h[2]  = fast_tanh(P0.z + Bq[2]);  h[3]  = fast_tanh(P0.w + Bq[3]);
    h[4]  = fast_tanh(P1.x + Bq[4]);  h[5]  = fast_tanh(P1.y + Bq[5]);
    h[6]  = fast_tanh(P1.z + Bq[6]);  h[7]  = fast_tanh(P1.w + Bq[7]);
    h[8]  = fast_tanh(P2.x + Bq[8]);  h[9]  = fast_tanh(P2.y + Bq[9]);
    h[10] = fast_tanh(P2.z + Bq[10]); h[11] = fast_tanh(P2.w + Bq[11]);
    h[12] = fast_tanh(P3.x + Bq[12]); h[13] = fast_tanh(P3.y + Bq[13]);
    h[14] = fast_tanh(P3.z + Bq[14]); h[15] = fast_tanh(P3.w + Bq[15]);
    h[16] = fast_tanh(P4.x + Bq[16]); h[17] = fast_tanh(P4.y + Bq[17]);
    asm volatile("" : "+v"(h[0]), "+v"(h[1]), "+v"(h[2]), "+v"(h[3]),
                      "+v"(h[4]), "+v"(h[5]), "+v"(h[6]), "+v"(h[7]),
                      "+v"(h[8]), "+v"(h[9]), "+v"(h[10]), "+v"(h[11]),
                      "+v"(h[12]), "+v"(h[13]), "+v"(h[14]), "+v"(h[15]),
                      "+v"(h[16]), "+v"(h[17]));
    float g[9];
#pragma unroll
    for (int o = 0; o < 9; ++o) g[o] = W[WP_B1 + o];
#pragma unroll
    for (int j = 0; j < 18; ++j) {
        const float a = h[j];
#pragma unroll
        for (int o = 0; o < 9; ++o) g[o] += a * W[WP_W1 + j * 9 + o];
    }
#pragma unroll
    for (int o = 0; o < 9; ++o) g[o] = fast_tanh(g[o]);
    asm volatile("" : "+v"(g[0]), "+v"(g[1]), "+v"(g[2]), "+v"(g[3]),
                      "+v"(g[4]), "+v"(g[5]), "+v"(g[6]), "+v"(g[7]),
                      "+v"(g[8]));
    float q[6];
#pragma unroll
    for (int o = 0; o < 6; ++o) q[o] = W[WP_B2 + o];
#pragma unroll
    for (int j = 0; j < 9; ++j) {
        const float a = g[j];
#pragma unroll
        for (int o = 0; o < 6; ++o) q[o] += a * W[WP_W2 + j * 6 + o];
    }
#pragma unroll
    for (int o = 0; o < 6; ++o) q[o] = fast_tanh(q[o]);
    asm volatile("" : "+v"(q[0]), "+v"(q[1]), "+v"(q[2]), "+v"(q[3]),
                      "+v"(q[4]), "+v"(q[5]));
    float o0 = W[WP_B3 + 0], o1 = W[WP_B3 + 1], o2 = W[WP_B3 + 2];
#pragma unroll
    for (int j = 0; j < 6; ++j) {
        const float a = q[j];
        o0 += a * W[WP_W3 + j * 3 + 0];
        o1 += a * W[WP_W3 + j * 3 + 1];
        o2 += a * W[WP_W3 + j * 3 + 2];
    }
    p0 += o0; p1 += o1; p2 += o2;
}

template <int ILP>
__device__ __forceinline__ void row_loop_pipe(const float* __restrict__ A,
                                              const unsigned short* __restrict__ lst,
                                              int cnt,
                                              const float* __restrict__ Bq,
                                              const float* __restrict__ W,
                                              int tid,
                                              float& p0, float& p1, float& p2) {
    int i = tid;
    if (i >= cnt) return;
    const float* r = A + (int)lst[i] * 20;
    float4 P0 = *(const float4*)(r);
    float4 P1 = *(const float4*)(r + 4);
    float4 P2 = *(const float4*)(r + 8);
    float4 P3 = *(const float4*)(r + 12);
    float2 P4 = *(const float2*)(r + 16);
    for (;;) {
        const int inext = i + 256;
        const bool more = inext < cnt;
        const float* rn = A + (int)lst[more ? inext : i] * 20;
        const float4 N0 = *(const float4*)(rn);
        const float4 N1 = *(const float4*)(rn + 4);
        const float4 N2 = *(const float4*)(rn + 8);
        const float4 N3 = *(const float4*)(rn + 12);
        const float2 N4 = *(const float2*)(rn + 16);
        if (ILP) eval_regs_ilp(P0, P1, P2, P3, P4, Bq, W, p0, p1, p2);
        else     eval_regs(P0, P1, P2, P3, P4, Bq, W, p0, p1, p2);
        if (!more) break;
        P0 = N0; P1 = N1; P2 = N2; P3 = N3; P4 = N4;
        i = inext;
    }
}

__global__ void prep_kernel(const int* __restrict__ index,
                            const float* __restrict__ data,
                            const float* __restrict__ wf0, const float* __restrict__ bf0,
                            const float* __restrict__ sw0, const float* __restrict__ sb0,
                            const float* __restrict__ wf1, const float* __restrict__ bf1,
                            const float* __restrict__ wf2, const float* __restrict__ bf2,
                            const float* __restrict__ wf3, const float* __restrict__ bf3,
                            const float* __restrict__ sw1, const float* __restrict__ sb1,
                            const float* __restrict__ sw2, const float* __restrict__ sb2,
                            const float* __restrict__ sw3, const float* __restrict__ sb3,
                            float* __restrict__ wsp) {
    int i = blockIdx.x * blockDim.x + threadIdx.x;
    if (i < NROWS) {
        float d[7], cen[7];
#pragma unroll
        for (int c = 0; c < 7; ++c) d[c] = data[i * 7 + c];
        int ci = index[i];
#pragma unroll
        for (int c = 0; c < 7; ++c) cen[c] = data[ci * 7 + c];
#pragma unroll
        for (int j = 0; j < 18; ++j) {
            float af = 0.f;
#pragma unroll
            for (int c = 0; c < 7; ++c) af += d[c] * wf0[c * 18 + j];
            float as = d[0] * sw0[0 * 18 + j] + d[1] * sw0[1 * 18 + j] + d[2] * sw0[2 * 18 + j];
            float bf = bf0[j], bs = sb0[j];
#pragma unroll
            for (int c = 0; c < 3; ++c) bf -= cen[c] * wf0[c * 18 + j];
#pragma unroll
            for (int c = 0; c < 4; ++c) bf += cen[3 + c] * wf0[(7 + c) * 18 + j];
#pragma unroll
            for (int c = 0; c < 3; ++c) bs -= cen[c] * sw0[c * 18 + j];
#pragma unroll
            for (int c = 0; c < 4; ++c) bs += cen[3 + c] * sw0[(3 + c) * 18 + j];
            wsp[OFF_AF + i * 20 + j] = af;
            wsp[OFF_AS + i * 20 + j] = as;
            wsp[OFF_BF + i * 20 + j] = bf;
            wsp[OFF_BS + i * 20 + j] = bs;
        }
        wsp[OFF_AF + i * 20 + 18] = 0.f; wsp[OFF_AF + i * 20 + 19] = 0.f;
        wsp[OFF_AS + i * 20 + 18] = 0.f; wsp[OFF_AS + i * 20 + 19] = 0.f;
        wsp[OFF_BF + i * 20 + 18] = 0.f; wsp[OFF_BF + i * 20 + 19] = 0.f;
        wsp[OFF_BS + i * 20 + 18] = 0.f; wsp[OFF_BS + i * 20 + 19] = 0.f;
    }
    if (blockIdx.x == 0) {
        int t = threadIdx.x;
        float* wp = wsp + OFF_WP;
        for (int k = t; k < 162; k += 256) wp[WP_W1 + k] = wf1[k];
        for (int k = t; k < 9;   k += 256) wp[WP_B1 + k] = bf1[k];
        for (int k = t; k < 54;  k += 256) wp[WP_W2 + k] = wf2[k];
        for (int k = t; k < 6;   k += 256) wp[WP_B2 + k] = bf2[k];
        for (int k = t; k < 18;  k += 256) wp[WP_W3 + k] = wf3[k];
        for (int k = t; k < 3;   k += 256) wp[WP_B3 + k] = bf3[k];
        for (int k = t; k < 162; k += 256) wp[WP_SOLID + WP_W1 + k] = sw1[k];
        for (int k = t; k < 9;   k += 256) wp[WP_SOLID + WP_B1 + k] = sb1[k];
        for (int k = t; k < 54;  k += 256) wp[WP_SOLID + WP_W2 + k] = sw2[k];
        for (int k = t; k < 6;   k += 256) wp[WP_SOLID + WP_B2 + k] = sb2[k];
        for (int k = t; k < 18;  k += 256) wp[WP_SOLID + WP_W3 + k] = sw3[k];
        for (int k = t; k < 3;   k += 256) wp[WP_SOLID + WP_B3 + k] = sb3[k];
    }
}

__global__ __launch_bounds__(256)
void compact_kernel(const int* __restrict__ mask,
                    const float* __restrict__ data,
                    float* __restrict__ wsp) {
    const int lane = threadIdx.x & 63;
    const int n = blockIdx.x * 4 + (threadIdx.x >> 6);
    int* counts_f = (int*)(wsp + OFF_CF);
    int* counts_s = (int*)(wsp + OFF_CS);
    unsigned short* lf = (unsigned short*)(wsp + OFF_LISTS) + (size_t)n * MCOLS;
    unsigned short* ls = lf + LF_CAP;
    const int* mrow = mask + (size_t)n * MCOLS;
    int bf = 0, bs = 0;
    const unsigned long long ltmask = (1ull << lane) - 1ull;
#pragma unroll 1
    for (int it = 0; it < MCOLS / 64; ++it) {
        const int m = it * 64 + lane;
        const int mk = mrow[m];
        const float flag = data[m * 7 + 6];
        const bool af = mk && (flag > 0.f);
        const bool as = mk && (flag < 1.f);
        const unsigned long long balf = __ballot(af);
        const unsigned long long bals = __ballot(as);
        if (af) lf[bf + __popcll(balf & ltmask)] = (unsigned short)m;
        if (as) ls[bs + __popcll(bals & ltmask)] = (unsigned short)m;
        bf += __popcll(balf);
        bs += __popcll(bals);
    }
    if (lane == 0) { counts_f[n] = bf; counts_s[n] = bs; }
}

template <int ILP>
__device__ __forceinline__ void main_body(const float* __restrict__ wsp,
                                          float* __restrict__ out) {
    const int n = blockIdx.x;
    const int tid = threadIdx.x;
    __shared__ float red[3][4];
    const float* __restrict__ W  = wsp + OFF_WP;
    const float* __restrict__ Bf = wsp + OFF_BF + n * 20;
    const float* __restrict__ Bs = wsp + OFF_BS + n * 20;
    const int cf = ((const int*)(wsp + OFF_CF))[n];
    const int cs = ((const int*)(wsp + OFF_CS))[n];
    const unsigned short* lf = (const unsigned short*)(wsp + OFF_LISTS) + (size_t)n * MCOLS;
    const unsigned short* ls = lf + LF_CAP;

    float p0 = 0.f, p1 = 0.f, p2 = 0.f;
    row_loop_pipe<ILP>(wsp + OFF_AF, lf, cf, Bf, W, tid, p0, p1, p2);
    row_loop_pipe<ILP>(wsp + OFF_AS, ls, cs, Bs, W + WP_SOLID, tid, p0, p1, p2);

#pragma unroll
    for (int off = 32; off > 0; off >>= 1) {
        p0 += __shfl_xor(p0, off, 64);
        p1 += __shfl_xor(p1, off, 64);
        p2 += __shfl_xor(p2, off, 64);
    }
    const int wid = tid >> 6;
    if ((tid & 63) == 0) { red[0][wid] = p0; red[1][wid] = p1; red[2][wid] = p2; }
    __syncthreads();
    if (tid == 0) {
        float s0 = 0.f, s1 = 0.f, s2 = 0.f;
#pragma unroll
        for (int w = 0; w < 4; ++w) { s0 += red[0][w]; s1 += red[1][w]; s2 += red[2][w]; }
        out[n * 3 + 0] = s0; out[n * 3 + 1] = s1; out[n * 3 + 2] = s2;
    }
}

// R11 A/B: layer-ILP fences vs control. Control runs LAST (validated).
__global__ __launch_bounds__(256, 4)
void main_ilp(const float* __restrict__ wsp, float* __restrict__ out) {
    main_body<1>(wsp, out);
}

__global__ __launch_bounds__(256, 4)
void main_pipe4(const float* __restrict__ wsp, float* __restrict__ out) {
    main_body<0>(wsp, out);
}

extern "C" void kernel_launch(void* const* d_in, const int* in_sizes, int n_in,
                              void* d_out, int out_size, void* d_ws, size_t ws_size,
                              hipStream_t stream) {
    const int*   mask  = (const int*)d_in[0];
    const int*   index = (const int*)d_in[1];
    const float* data  = (const float*)d_in[2];
    const float* wf0   = (const float*)d_in[3];
    const float* bf0   = (const float*)d_in[4];
    const float* wf1   = (const float*)d_in[5];
    const float* bf1   = (const float*)d_in[6];
    const float* wf2   = (const float*)d_in[7];
    const float* bf2   = (const float*)d_in[8];
    const float* wf3   = (const float*)d_in[9];
    const float* bf3   = (const float*)d_in[10];
    const float* sw0   = (const float*)d_in[11];
    const float* sb0   = (const float*)d_in[12];
    const float* sw1   = (const float*)d_in[13];
    const float* sb1   = (const float*)d_in[14];
    const float* sw2   = (const float*)d_in[15];
    const float* sb2   = (const float*)d_in[16];
    const float* sw3   = (const float*)d_in[17];
    const float* sb3   = (const float*)d_in[18];
    float* wsp = (float*)d_ws;
    float* out = (float*)d_out;

    prep_kernel<<<dim3(8), dim3(256), 0, stream>>>(
        index, data, wf0, bf0, sw0, sb0, wf1, bf1, wf2, bf2, wf3, bf3,
        sw1, sb1, sw2, sb2, sw3, sb3, wsp);
    compact_kernel<<<dim3(NROWS / 4), dim3(256), 0, stream>>>(mask, data, wsp);
    main_ilp<<<dim3(NROWS), dim3(256), 0, stream>>>(wsp, out);
    main_pipe4<<<dim3(NROWS), dim3(256), 0, stream>>>(wsp, out);
}

// Round 12
// 116.179 us; speedup vs baseline: 2.2570x; 1.2668x over previous
//
#include <hip/hip_runtime.h>

#define NROWS 2048
#define MCOLS 2048

// ---- d_ws layout (float offsets); rows padded to stride 20 ----
#define OFF_AF 0
#define OFF_AS (OFF_AF + NROWS * 20)
#define OFF_BF (OFF_AS + NROWS * 20)
#define OFF_BS (OFF_BF + NROWS * 20)
#define OFF_WP (OFF_BS + NROWS * 20)
#define OFF_CF (OFF_WP + 512)
#define OFF_CS (OFF_CF + NROWS)
#define OFF_LISTS (OFF_CS + NROWS)
#define LF_CAP ((size_t)NROWS * MCOLS)

#define WP_W1 0
#define WP_B1 162
#define WP_W2 171
#define WP_B2 225
#define WP_W3 231
#define WP_B3 249
#define WP_SOLID 252

typedef float v2f __attribute__((ext_vector_type(2)));
__device__ __forceinline__ v2f SP(float s) { return (v2f){s, s}; }

// exp2-based tanh: absmax 0.5 verified R1-R11. (Pade 3/3 FAILED in R5.)
__device__ __forceinline__ float fast_tanh(float x) {
    float t = __builtin_amdgcn_exp2f(x * 2.8853900817779268f);
    return 1.0f - 2.0f * __builtin_amdgcn_rcpf(1.0f + t);
}

__device__ __forceinline__ v2f vtanh(v2f x) {
    v2f xs = x * SP(2.8853900817779268f);
    v2f t;
    t.x = __builtin_amdgcn_exp2f(xs.x);
    t.y = __builtin_amdgcn_exp2f(xs.y);
    v2f d = t + SP(1.0f);
    v2f r;
    r.x = __builtin_amdgcn_rcpf(d.x);
    r.y = __builtin_amdgcn_rcpf(d.y);
    return SP(1.0f) - SP(2.0f) * r;
}

// ---------- champion eval: scalar + layer-ILP fences (R11 winner) ----------
__device__ __forceinline__ void eval_regs_ilp(float4 P0, float4 P1, float4 P2,
                                              float4 P3, float2 P4,
                                              const float* __restrict__ Bq,
                                              const float* __restrict__ W,
                                              float& p0, float& p1, float& p2) {
    float h[18];
    h[0]  = fast_tanh(P0.x + Bq[0]);  h[1]  = fast_tanh(P0.y + Bq[1]);
    h[2]  = fast_tanh(P0.z + Bq[2]);  h[3]  = fast_tanh(P0.w + Bq[3]);
    h[4]  = fast_tanh(P1.x + Bq[4]);  h[5]  = fast_tanh(P1.y + Bq[5]);
    h[6]  = fast_tanh(P1.z + Bq[6]);  h[7]  = fast_tanh(P1.w + Bq[7]);
    h[8]  = fast_tanh(P2.x + Bq[8]);  h[9]  = fast_tanh(P2.y + Bq[9]);
    h[10] = fast_tanh(P2.z + Bq[10]); h[11] = fast_tanh(P2.w + Bq[11]);
    h[12] = fast_tanh(P3.x + Bq[12]); h[13] = fast_tanh(P3.y + Bq[13]);
    h[14] = fast_tanh(P3.z + Bq[14]); h[15] = fast_tanh(P3.w + Bq[15]);
    h[16] = fast_tanh(P4.x + Bq[16]); h[17] = fast_tanh(P4.y + Bq[17]);
    asm volatile("" : "+v"(h[0]), "+v"(h[1]), "+v"(h[2]), "+v"(h[3]),
                      "+v"(h[4]), "+v"(h[5]), "+v"(h[6]), "+v"(h[7]),
                      "+v"(h[8]), "+v"(h[9]), "+v"(h[10]), "+v"(h[11]),
                      "+v"(h[12]), "+v"(h[13]), "+v"(h[14]), "+v"(h[15]),
                      "+v"(h[16]), "+v"(h[17]));
    float g[9];
#pragma unroll
    for (int o = 0; o < 9; ++o) g[o] = W[WP_B1 + o];
#pragma unroll
    for (int j = 0; j < 18; ++j) {
        const float a = h[j];
#pragma unroll
        for (int o = 0; o < 9; ++o) g[o] += a * W[WP_W1 + j * 9 + o];
    }
#pragma unroll
    for (int o = 0; o < 9; ++o) g[o] = fast_tanh(g[o]);
    asm volatile("" : "+v"(g[0]), "+v"(g[1]), "+v"(g[2]), "+v"(g[3]),
                      "+v"(g[4]), "+v"(g[5]), "+v"(g[6]), "+v"(g[7]),
                      "+v"(g[8]));
    float q[6];
#pragma unroll
    for (int o = 0; o < 6; ++o) q[o] = W[WP_B2 + o];
#pragma unroll
    for (int j = 0; j < 9; ++j) {
        const float a = g[j];
#pragma unroll
        for (int o = 0; o < 6; ++o) q[o] += a * W[WP_W2 + j * 6 + o];
    }
#pragma unroll
    for (int o = 0; o < 6; ++o) q[o] = fast_tanh(q[o]);
    asm volatile("" : "+v"(q[0]), "+v"(q[1]), "+v"(q[2]), "+v"(q[3]),
                      "+v"(q[4]), "+v"(q[5]));
    float o0 = W[WP_B3 + 0], o1 = W[WP_B3 + 1], o2 = W[WP_B3 + 2];
#pragma unroll
    for (int j = 0; j < 6; ++j) {
        const float a = q[j];
        o0 += a * W[WP_W3 + j * 3 + 0];
        o1 += a * W[WP_W3 + j * 3 + 1];
        o2 += a * W[WP_W3 + j * 3 + 2];
    }
    p0 += o0; p1 += o1; p2 += o2;
}

// ---------- experiment eval: pk pair + layer-ILP fences ----------
__device__ __forceinline__ void eval_pair_ilp(const float* __restrict__ A,
                                              int m0, int m1,
                                              const float* __restrict__ Bq,
                                              const float* __restrict__ W,
                                              v2f& s0, v2f& s1, v2f& s2) {
    const float* r0 = A + m0 * 20;
    const float* r1 = A + m1 * 20;
    const float4 X0 = *(const float4*)(r0);
    const float4 X1 = *(const float4*)(r0 + 4);
    const float4 X2 = *(const float4*)(r0 + 8);
    const float4 X3 = *(const float4*)(r0 + 12);
    const float2 X4 = *(const float2*)(r0 + 16);
    const float4 Y0 = *(const float4*)(r1);
    const float4 Y1 = *(const float4*)(r1 + 4);
    const float4 Y2 = *(const float4*)(r1 + 8);
    const float4 Y3 = *(const float4*)(r1 + 12);
    const float2 Y4 = *(const float2*)(r1 + 16);
    v2f h[18];
    h[0]  = vtanh((v2f){X0.x, Y0.x} + SP(Bq[0]));
    h[1]  = vtanh((v2f){X0.y, Y0.y} + SP(Bq[1]));
    h[2]  = vtanh((v2f){X0.z, Y0.z} + SP(Bq[2]));
    h[3]  = vtanh((v2f){X0.w, Y0.w} + SP(Bq[3]));
    h[4]  = vtanh((v2f){X1.x, Y1.x} + SP(Bq[4]));
    h[5]  = vtanh((v2f){X1.y, Y1.y} + SP(Bq[5]));
    h[6]  = vtanh((v2f){X1.z, Y1.z} + SP(Bq[6]));
    h[7]  = vtanh((v2f){X1.w, Y1.w} + SP(Bq[7]));
    h[8]  = vtanh((v2f){X2.x, Y2.x} + SP(Bq[8]));
    h[9]  = vtanh((v2f){X2.y, Y2.y} + SP(Bq[9]));
    h[10] = vtanh((v2f){X2.z, Y2.z} + SP(Bq[10]));
    h[11] = vtanh((v2f){X2.w, Y2.w} + SP(Bq[11]));
    h[12] = vtanh((v2f){X3.x, Y3.x} + SP(Bq[12]));
    h[13] = vtanh((v2f){X3.y, Y3.y} + SP(Bq[13]));
    h[14] = vtanh((v2f){X3.z, Y3.z} + SP(Bq[14]));
    h[15] = vtanh((v2f){X3.w, Y3.w} + SP(Bq[15]));
    h[16] = vtanh((v2f){X4.x, Y4.x} + SP(Bq[16]));
    h[17] = vtanh((v2f){X4.y, Y4.y} + SP(Bq[17]));
    asm volatile("" : "+v"(h[0]), "+v"(h[1]), "+v"(h[2]), "+v"(h[3]),
                      "+v"(h[4]), "+v"(h[5]), "+v"(h[6]), "+v"(h[7]),
                      "+v"(h[8]), "+v"(h[9]), "+v"(h[10]), "+v"(h[11]),
                      "+v"(h[12]), "+v"(h[13]), "+v"(h[14]), "+v"(h[15]),
                      "+v"(h[16]), "+v"(h[17]));
    v2f g[9];
#pragma unroll
    for (int o = 0; o < 9; ++o) g[o] = SP(W[WP_B1 + o]);
#pragma unroll
    for (int j = 0; j < 18; ++j) {
        const v2f a = h[j];
#pragma unroll
        for (int o = 0; o < 9; ++o) g[o] += a * SP(W[WP_W1 + j * 9 + o]);
    }
#pragma unroll
    for (int o = 0; o < 9; ++o) g[o] = vtanh(g[o]);
    asm volatile("" : "+v"(g[0]), "+v"(g[1]), "+v"(g[2]), "+v"(g[3]),
                      "+v"(g[4]), "+v"(g[5]), "+v"(g[6]), "+v"(g[7]),
                      "+v"(g[8]));
    v2f q[6];
#pragma unroll
    for (int o = 0; o < 6; ++o) q[o] = SP(W[WP_B2 + o]);
#pragma unroll
    for (int j = 0; j < 9; ++j) {
        const v2f a = g[j];
#pragma unroll
        for (int o = 0; o < 6; ++o) q[o] += a * SP(W[WP_W2 + j * 6 + o]);
    }
#pragma unroll
    for (int o = 0; o < 6; ++o) q[o] = vtanh(q[o]);
    asm volatile("" : "+v"(q[0]), "+v"(q[1]), "+v"(q[2]), "+v"(q[3]),
                      "+v"(q[4]), "+v"(q[5]));
    v2f o0 = SP(W[WP_B3 + 0]), o1 = SP(W[WP_B3 + 1]), o2 = SP(W[WP_B3 + 2]);
#pragma unroll
    for (int j = 0; j < 6; ++j) {
        const v2f a = q[j];
        o0 += a * SP(W[WP_W3 + j * 3 + 0]);
        o1 += a * SP(W[WP_W3 + j * 3 + 1]);
        o2 += a * SP(W[WP_W3 + j * 3 + 2]);
    }
    s0 += o0; s1 += o1; s2 += o2;
}

__device__ __forceinline__ void eval_single_ilp(const float* __restrict__ A, int m,
                                                const float* __restrict__ Bq,
                                                const float* __restrict__ W,
                                                float& p0, float& p1, float& p2) {
    const float* r = A + m * 20;
    eval_regs_ilp(*(const float4*)(r), *(const float4*)(r + 4),
                  *(const float4*)(r + 8), *(const float4*)(r + 12),
                  *(const float2*)(r + 16), Bq, W, p0, p1, p2);
}

// champion loop: scalar ILP + 2-deep prefetch
__device__ __forceinline__ void row_loop_ilp(const float* __restrict__ A,
                                             const unsigned short* __restrict__ lst,
                                             int cnt,
                                             const float* __restrict__ Bq,
                                             const float* __restrict__ W,
                                             int tid,
                                             float& p0, float& p1, float& p2) {
    int i = tid;
    if (i >= cnt) return;
    const float* r = A + (int)lst[i] * 20;
    float4 P0 = *(const float4*)(r);
    float4 P1 = *(const float4*)(r + 4);
    float4 P2 = *(const float4*)(r + 8);
    float4 P3 = *(const float4*)(r + 12);
    float2 P4 = *(const float2*)(r + 16);
    for (;;) {
        const int inext = i + 256;
        const bool more = inext < cnt;
        const float* rn = A + (int)lst[more ? inext : i] * 20;
        const float4 N0 = *(const float4*)(rn);
        const float4 N1 = *(const float4*)(rn + 4);
        const float4 N2 = *(const float4*)(rn + 8);
        const float4 N3 = *(const float4*)(rn + 12);
        const float2 N4 = *(const float2*)(rn + 16);
        eval_regs_ilp(P0, P1, P2, P3, P4, Bq, W, p0, p1, p2);
        if (!more) break;
        P0 = N0; P1 = N1; P2 = N2; P3 = N3; P4 = N4;
        i = inext;
    }
}

// experiment loop: pk pair + ILP fences
__device__ __forceinline__ void row_loop_pair_ilp(const float* __restrict__ A,
                                                  const unsigned short* __restrict__ lst,
                                                  int cnt,
                                                  const float* __restrict__ Bq,
                                                  const float* __restrict__ W,
                                                  int tid,
                                                  v2f& s0, v2f& s1, v2f& s2,
                                                  float& p0, float& p1, float& p2) {
    const unsigned int* l32 = (const unsigned int*)lst;
    const int np = cnt >> 1;
#pragma unroll 1
    for (int i = tid; i < np; i += 256) {
        const unsigned int mm = l32[i];
        eval_pair_ilp(A, (int)(mm & 0xffffu), (int)(mm >> 16), Bq, W, s0, s1, s2);
    }
    if ((cnt & 1) && tid == 0)
        eval_single_ilp(A, lst[cnt - 1], Bq, W, p0, p1, p2);
}

__global__ void prep_kernel(const int* __restrict__ index,
                            const float* __restrict__ data,
                            const float* __restrict__ wf0, const float* __restrict__ bf0,
                            const float* __restrict__ sw0, const float* __restrict__ sb0,
                            const float* __restrict__ wf1, const float* __restrict__ bf1,
                            const float* __restrict__ wf2, const float* __restrict__ bf2,
                            const float* __restrict__ wf3, const float* __restrict__ bf3,
                            const float* __restrict__ sw1, const float* __restrict__ sb1,
                            const float* __restrict__ sw2, const float* __restrict__ sb2,
                            const float* __restrict__ sw3, const float* __restrict__ sb3,
                            float* __restrict__ wsp) {
    int i = blockIdx.x * blockDim.x + threadIdx.x;
    if (i < NROWS) {
        float d[7], cen[7];
#pragma unroll
        for (int c = 0; c < 7; ++c) d[c] = data[i * 7 + c];
        int ci = index[i];
#pragma unroll
        for (int c = 0; c < 7; ++c) cen[c] = data[ci * 7 + c];
#pragma unroll
        for (int j = 0; j < 18; ++j) {
            float af = 0.f;
#pragma unroll
            for (int c = 0; c < 7; ++c) af += d[c] * wf0[c * 18 + j];
            float as = d[0] * sw0[0 * 18 + j] + d[1] * sw0[1 * 18 + j] + d[2] * sw0[2 * 18 + j];
            float bf = bf0[j], bs = sb0[j];
#pragma unroll
            for (int c = 0; c < 3; ++c) bf -= cen[c] * wf0[c * 18 + j];
#pragma unroll
            for (int c = 0; c < 4; ++c) bf += cen[3 + c] * wf0[(7 + c) * 18 + j];
#pragma unroll
            for (int c = 0; c < 3; ++c) bs -= cen[c] * sw0[c * 18 + j];
#pragma unroll
            for (int c = 0; c < 4; ++c) bs += cen[3 + c] * sw0[(3 + c) * 18 + j];
            wsp[OFF_AF + i * 20 + j] = af;
            wsp[OFF_AS + i * 20 + j] = as;
            wsp[OFF_BF + i * 20 + j] = bf;
            wsp[OFF_BS + i * 20 + j] = bs;
        }
        wsp[OFF_AF + i * 20 + 18] = 0.f; wsp[OFF_AF + i * 20 + 19] = 0.f;
        wsp[OFF_AS + i * 20 + 18] = 0.f; wsp[OFF_AS + i * 20 + 19] = 0.f;
        wsp[OFF_BF + i * 20 + 18] = 0.f; wsp[OFF_BF + i * 20 + 19] = 0.f;
        wsp[OFF_BS + i * 20 + 18] = 0.f; wsp[OFF_BS + i * 20 + 19] = 0.f;
    }
    if (blockIdx.x == 0) {
        int t = threadIdx.x;
        float* wp = wsp + OFF_WP;
        for (int k = t; k < 162; k += 256) wp[WP_W1 + k] = wf1[k];
        for (int k = t; k < 9;   k += 256) wp[WP_B1 + k] = bf1[k];
        for (int k = t; k < 54;  k += 256) wp[WP_W2 + k] = wf2[k];
        for (int k = t; k < 6;   k += 256) wp[WP_B2 + k] = bf2[k];
        for (int k = t; k < 18;  k += 256) wp[WP_W3 + k] = wf3[k];
        for (int k = t; k < 3;   k += 256) wp[WP_B3 + k] = bf3[k];
        for (int k = t; k < 162; k += 256) wp[WP_SOLID + WP_W1 + k] = sw1[k];
        for (int k = t; k < 9;   k += 256) wp[WP_SOLID + WP_B1 + k] = sb1[k];
        for (int k = t; k < 54;  k += 256) wp[WP_SOLID + WP_W2 + k] = sw2[k];
        for (int k = t; k < 6;   k += 256) wp[WP_SOLID + WP_B2 + k] = sb2[k];
        for (int k = t; k < 18;  k += 256) wp[WP_SOLID + WP_W3 + k] = sw3[k];
        for (int k = t; k < 3;   k += 256) wp[WP_SOLID + WP_B3 + k] = sb3[k];
    }
}

__global__ __launch_bounds__(256)
void compact_kernel(const int* __restrict__ mask,
                    const float* __restrict__ data,
                    float* __restrict__ wsp) {
    const int lane = threadIdx.x & 63;
    const int n = blockIdx.x * 4 + (threadIdx.x >> 6);
    int* counts_f = (int*)(wsp + OFF_CF);
    int* counts_s = (int*)(wsp + OFF_CS);
    unsigned short* lf = (unsigned short*)(wsp + OFF_LISTS) + (size_t)n * MCOLS;
    unsigned short* ls = lf + LF_CAP;
    const int* mrow = mask + (size_t)n * MCOLS;
    int bf = 0, bs = 0;
    const unsigned long long ltmask = (1ull << lane) - 1ull;
#pragma unroll 1
    for (int it = 0; it < MCOLS / 64; ++it) {
        const int m = it * 64 + lane;
        const int mk = mrow[m];
        const float flag = data[m * 7 + 6];
        const bool af = mk && (flag > 0.f);
        const bool as = mk && (flag < 1.f);
        const unsigned long long balf = __ballot(af);
        const unsigned long long bals = __ballot(as);
        if (af) lf[bf + __popcll(balf & ltmask)] = (unsigned short)m;
        if (as) ls[bs + __popcll(bals & ltmask)] = (unsigned short)m;
        bf += __popcll(balf);
        bs += __popcll(bals);
    }
    if (lane == 0) { counts_f[n] = bf; counts_s[n] = bs; }
}

// experiment kernel
__global__ __launch_bounds__(256, 4)
void main_pk_ilp(const float* __restrict__ wsp, float* __restrict__ out) {
    const int n = blockIdx.x;
    const int tid = threadIdx.x;
    __shared__ float red[3][4];
    const float* __restrict__ W  = wsp + OFF_WP;
    const float* __restrict__ Bf = wsp + OFF_BF + n * 20;
    const float* __restrict__ Bs = wsp + OFF_BS + n * 20;
    const int cf = ((const int*)(wsp + OFF_CF))[n];
    const int cs = ((const int*)(wsp + OFF_CS))[n];
    const unsigned short* lf = (const unsigned short*)(wsp + OFF_LISTS) + (size_t)n * MCOLS;
    const unsigned short* ls = lf + LF_CAP;

    float p0 = 0.f, p1 = 0.f, p2 = 0.f;
    v2f s0 = SP(0.f), s1 = SP(0.f), s2 = SP(0.f);
    row_loop_pair_ilp(wsp + OFF_AF, lf, cf, Bf, W, tid, s0, s1, s2, p0, p1, p2);
    row_loop_pair_ilp(wsp + OFF_AS, ls, cs, Bs, W + WP_SOLID, tid, s0, s1, s2, p0, p1, p2);
    p0 += s0.x + s0.y; p1 += s1.x + s1.y; p2 += s2.x + s2.y;

#pragma unroll
    for (int off = 32; off > 0; off >>= 1) {
        p0 += __shfl_xor(p0, off, 64);
        p1 += __shfl_xor(p1, off, 64);
        p2 += __shfl_xor(p2, off, 64);
    }
    const int wid = tid >> 6;
    if ((tid & 63) == 0) { red[0][wid] = p0; red[1][wid] = p1; red[2][wid] = p2; }
    __syncthreads();
    if (tid == 0) {
        float a0 = 0.f, a1 = 0.f, a2 = 0.f;
#pragma unroll
        for (int w = 0; w < 4; ++w) { a0 += red[0][w]; a1 += red[1][w]; a2 += red[2][w]; }
        out[n * 3 + 0] = a0; out[n * 3 + 1] = a1; out[n * 3 + 2] = a2;
    }
}

// champion kernel (R11 winner), runs LAST -> validated.
__global__ __launch_bounds__(256, 4)
void main_ilp(const float* __restrict__ wsp, float* __restrict__ out) {
    const int n = blockIdx.x;
    const int tid = threadIdx.x;
    __shared__ float red[3][4];
    const float* __restrict__ W  = wsp + OFF_WP;
    const float* __restrict__ Bf = wsp + OFF_BF + n * 20;
    const float* __restrict__ Bs = wsp + OFF_BS + n * 20;
    const int cf = ((const int*)(wsp + OFF_CF))[n];
    const int cs = ((const int*)(wsp + OFF_CS))[n];
    const unsigned short* lf = (const unsigned short*)(wsp + OFF_LISTS) + (size_t)n * MCOLS;
    const unsigned short* ls = lf + LF_CAP;

    float p0 = 0.f, p1 = 0.f, p2 = 0.f;
    row_loop_ilp(wsp + OFF_AF, lf, cf, Bf, W, tid, p0, p1, p2);
    row_loop_ilp(wsp + OFF_AS, ls, cs, Bs, W + WP_SOLID, tid, p0, p1, p2);

#pragma unroll
    for (int off = 32; off > 0; off >>= 1) {
        p0 += __shfl_xor(p0, off, 64);
        p1 += __shfl_xor(p1, off, 64);
        p2 += __shfl_xor(p2, off, 64);
    }
    const int wid = tid >> 6;
    if ((tid & 63) == 0) { red[0][wid] = p0; red[1][wid] = p1; red[2][wid] = p2; }
    __syncthreads();
    if (tid == 0) {
        float a0 = 0.f, a1 = 0.f, a2 = 0.f;
#pragma unroll
        for (int w = 0; w < 4; ++w) { a0 += red[0][w]; a1 += red[1][w]; a2 += red[2][w]; }
        out[n * 3 + 0] = a0; out[n * 3 + 1] = a1; out[n * 3 + 2] = a2;
    }
}

extern "C" void kernel_launch(void* const* d_in, const int* in_sizes, int n_in,
                              void* d_out, int out_size, void* d_ws, size_t ws_size,
                              hipStream_t stream) {
    const int*   mask  = (const int*)d_in[0];
    const int*   index = (const int*)d_in[1];
    const float* data  = (const float*)d_in[2];
    const float* wf0   = (const float*)d_in[3];
    const float* bf0   = (const float*)d_in[4];
    const float* wf1   = (const float*)d_in[5];
    const float* bf1   = (const float*)d_in[6];
    const float* wf2   = (const float*)d_in[7];
    const float* bf2   = (const float*)d_in[8];
    const float* wf3   = (const float*)d_in[9];
    const float* bf3   = (const float*)d_in[10];
    const float* sw0   = (const float*)d_in[11];
    const float* sb0   = (const float*)d_in[12];
    const float* sw1   = (const float*)d_in[13];
    const float* sb1   = (const float*)d_in[14];
    const float* sw2   = (const float*)d_in[15];
    const float* sb2   = (const float*)d_in[16];
    const float* sw3   = (const float*)d_in[17];
    const float* sb3   = (const float*)d_in[18];
    float* wsp = (float*)d_ws;
    float* out = (float*)d_out;

    prep_kernel<<<dim3(8), dim3(256), 0, stream>>>(
        index, data, wf0, bf0, sw0, sb0, wf1, bf1, wf2, bf2, wf3, bf3,
        sw1, sb1, sw2, sb2, sw3, sb3, wsp);
    compact_kernel<<<dim3(NROWS / 4), dim3(256), 0, stream>>>(mask, data, wsp);
    main_pk_ilp<<<dim3(NROWS), dim3(256), 0, stream>>>(wsp, out);
    main_ilp<<<dim3(NROWS), dim3(256), 0, stream>>>(wsp, out);
}

// Round 13
// 70.168 us; speedup vs baseline: 3.7370x; 1.6557x over previous
//
#include <hip/hip_runtime.h>

#define NROWS 2048
#define MCOLS 2048

// ---- d_ws layout (float offsets); rows padded to stride 20 ----
#define OFF_AF 0
#define OFF_AS (OFF_AF + NROWS * 20)
#define OFF_BF (OFF_AS + NROWS * 20)
#define OFF_BS (OFF_BF + NROWS * 20)
#define OFF_WP (OFF_BS + NROWS * 20)
#define OFF_CF (OFF_WP + 512)
#define OFF_CS (OFF_CF + NROWS)
#define OFF_LISTS (OFF_CS + NROWS)
#define LF_CAP ((size_t)NROWS * MCOLS)

#define WP_W1 0
#define WP_B1 162
#define WP_W2 171
#define WP_B2 225
#define WP_W3 231
#define WP_B3 249
#define WP_SOLID 252

// exp2-based tanh: absmax 0.5 verified R1-R12. (Pade 3/3 FAILED in R5:
// systematic per-activation error × ~1400-term masked sum -> 48 abs.)
__device__ __forceinline__ float fast_tanh(float x) {
    float t = __builtin_amdgcn_exp2f(x * 2.8853900817779268f);
    return 1.0f - 2.0f * __builtin_amdgcn_rcpf(1.0f + t);
}

// Champion eval (R11): scalar math + layer-ILP asm fences.
// The fences force all 18 (then 9, 6) activations simultaneously live so the
// compiler cannot re-serialize the independent tanh chains to save VGPRs
// (that serialization was the hidden 1.7x cost through R10).
__device__ __forceinline__ void eval_regs_ilp(float4 P0, float4 P1, float4 P2,
                                              float4 P3, float2 P4,
                                              const float* __restrict__ Bq,
                                              const float* __restrict__ W,
                                              float& p0, float& p1, float& p2) {
    float h[18];
    h[0]  = fast_tanh(P0.x + Bq[0]);  h[1]  = fast_tanh(P0.y + Bq[1]);
    h[2]  = fast_tanh(P0.z + Bq[2]);  h[3]  = fast_tanh(P0.w + Bq[3]);
    h[4]  = fast_tanh(P1.x + Bq[4]);  h[5]  = fast_tanh(P1.y + Bq[5]);
    h[6]  = fast_tanh(P1.z + Bq[6]);  h[7]  = fast_tanh(P1.w + Bq[7]);
    h[8]  = fast_tanh(P2.x + Bq[8]);  h[9]  = fast_tanh(P2.y + Bq[9]);
    h[10] = fast_tanh(P2.z + Bq[10]); h[11] = fast_tanh(P2.w + Bq[11]);
    h[12] = fast_tanh(P3.x + Bq[12]); h[13] = fast_tanh(P3.y + Bq[13]);
    h[14] = fast_tanh(P3.z + Bq[14]); h[15] = fast_tanh(P3.w + Bq[15]);
    h[16] = fast_tanh(P4.x + Bq[16]); h[17] = fast_tanh(P4.y + Bq[17]);
    asm volatile("" : "+v"(h[0]), "+v"(h[1]), "+v"(h[2]), "+v"(h[3]),
                      "+v"(h[4]), "+v"(h[5]), "+v"(h[6]), "+v"(h[7]),
                      "+v"(h[8]), "+v"(h[9]), "+v"(h[10]), "+v"(h[11]),
                      "+v"(h[12]), "+v"(h[13]), "+v"(h[14]), "+v"(h[15]),
                      "+v"(h[16]), "+v"(h[17]));
    float g[9];
#pragma unroll
    for (int o = 0; o < 9; ++o) g[o] = W[WP_B1 + o];
#pragma unroll
    for (int j = 0; j < 18; ++j) {
        const float a = h[j];
#pragma unroll
        for (int o = 0; o < 9; ++o) g[o] += a * W[WP_W1 + j * 9 + o];
    }
#pragma unroll
    for (int o = 0; o < 9; ++o) g[o] = fast_tanh(g[o]);
    asm volatile("" : "+v"(g[0]), "+v"(g[1]), "+v"(g[2]), "+v"(g[3]),
                      "+v"(g[4]), "+v"(g[5]), "+v"(g[6]), "+v"(g[7]),
                      "+v"(g[8]));
    float q[6];
#pragma unroll
    for (int o = 0; o < 6; ++o) q[o] = W[WP_B2 + o];
#pragma unroll
    for (int j = 0; j < 9; ++j) {
        const float a = g[j];
#pragma unroll
        for (int o = 0; o < 6; ++o) q[o] += a * W[WP_W2 + j * 6 + o];
    }
#pragma unroll
    for (int o = 0; o < 6; ++o) q[o] = fast_tanh(q[o]);
    asm volatile("" : "+v"(q[0]), "+v"(q[1]), "+v"(q[2]), "+v"(q[3]),
                      "+v"(q[4]), "+v"(q[5]));
    float o0 = W[WP_B3 + 0], o1 = W[WP_B3 + 1], o2 = W[WP_B3 + 2];
#pragma unroll
    for (int j = 0; j < 6; ++j) {
        const float a = q[j];
        o0 += a * W[WP_W3 + j * 3 + 0];
        o1 += a * W[WP_W3 + j * 3 + 1];
        o2 += a * W[WP_W3 + j * 3 + 2];
    }
    p0 += o0; p1 += o1; p2 += o2;
}

// champion loop: scalar ILP eval + 2-deep register prefetch of next A-row.
__device__ __forceinline__ void row_loop_ilp(const float* __restrict__ A,
                                             const unsigned short* __restrict__ lst,
                                             int cnt,
                                             const float* __restrict__ Bq,
                                             const float* __restrict__ W,
                                             int tid,
                                             float& p0, float& p1, float& p2) {
    int i = tid;
    if (i >= cnt) return;
    const float* r = A + (int)lst[i] * 20;
    float4 P0 = *(const float4*)(r);
    float4 P1 = *(const float4*)(r + 4);
    float4 P2 = *(const float4*)(r + 8);
    float4 P3 = *(const float4*)(r + 12);
    float2 P4 = *(const float2*)(r + 16);
    for (;;) {
        const int inext = i + 256;
        const bool more = inext < cnt;
        const float* rn = A + (int)lst[more ? inext : i] * 20;
        const float4 N0 = *(const float4*)(rn);
        const float4 N1 = *(const float4*)(rn + 4);
        const float4 N2 = *(const float4*)(rn + 8);
        const float4 N3 = *(const float4*)(rn + 12);
        const float2 N4 = *(const float2*)(rn + 16);
        eval_regs_ilp(P0, P1, P2, P3, P4, Bq, W, p0, p1, p2);
        if (!more) break;
        P0 = N0; P1 = N1; P2 = N2; P3 = N3; P4 = N4;
        i = inext;
    }
}

__global__ void prep_kernel(const int* __restrict__ index,
                            const float* __restrict__ data,
                            const float* __restrict__ wf0, const float* __restrict__ bf0,
                            const float* __restrict__ sw0, const float* __restrict__ sb0,
                            const float* __restrict__ wf1, const float* __restrict__ bf1,
                            const float* __restrict__ wf2, const float* __restrict__ bf2,
                            const float* __restrict__ wf3, const float* __restrict__ bf3,
                            const float* __restrict__ sw1, const float* __restrict__ sb1,
                            const float* __restrict__ sw2, const float* __restrict__ sb2,
                            const float* __restrict__ sw3, const float* __restrict__ sb3,
                            float* __restrict__ wsp) {
    int i = blockIdx.x * blockDim.x + threadIdx.x;
    if (i < NROWS) {
        float d[7], cen[7];
#pragma unroll
        for (int c = 0; c < 7; ++c) d[c] = data[i * 7 + c];
        int ci = index[i];
#pragma unroll
        for (int c = 0; c < 7; ++c) cen[c] = data[ci * 7 + c];
#pragma unroll
        for (int j = 0; j < 18; ++j) {
            float af = 0.f;
#pragma unroll
            for (int c = 0; c < 7; ++c) af += d[c] * wf0[c * 18 + j];
            float as = d[0] * sw0[0 * 18 + j] + d[1] * sw0[1 * 18 + j] + d[2] * sw0[2 * 18 + j];
            float bf = bf0[j], bs = sb0[j];
#pragma unroll
            for (int c = 0; c < 3; ++c) bf -= cen[c] * wf0[c * 18 + j];
#pragma unroll
            for (int c = 0; c < 4; ++c) bf += cen[3 + c] * wf0[(7 + c) * 18 + j];
#pragma unroll
            for (int c = 0; c < 3; ++c) bs -= cen[c] * sw0[c * 18 + j];
#pragma unroll
            for (int c = 0; c < 4; ++c) bs += cen[3 + c] * sw0[(3 + c) * 18 + j];
            wsp[OFF_AF + i * 20 + j] = af;
            wsp[OFF_AS + i * 20 + j] = as;
            wsp[OFF_BF + i * 20 + j] = bf;
            wsp[OFF_BS + i * 20 + j] = bs;
        }
        wsp[OFF_AF + i * 20 + 18] = 0.f; wsp[OFF_AF + i * 20 + 19] = 0.f;
        wsp[OFF_AS + i * 20 + 18] = 0.f; wsp[OFF_AS + i * 20 + 19] = 0.f;
        wsp[OFF_BF + i * 20 + 18] = 0.f; wsp[OFF_BF + i * 20 + 19] = 0.f;
        wsp[OFF_BS + i * 20 + 18] = 0.f; wsp[OFF_BS + i * 20 + 19] = 0.f;
    }
    if (blockIdx.x == 0) {
        int t = threadIdx.x;
        float* wp = wsp + OFF_WP;
        for (int k = t; k < 162; k += 256) wp[WP_W1 + k] = wf1[k];
        for (int k = t; k < 9;   k += 256) wp[WP_B1 + k] = bf1[k];
        for (int k = t; k < 54;  k += 256) wp[WP_W2 + k] = wf2[k];
        for (int k = t; k < 6;   k += 256) wp[WP_B2 + k] = bf2[k];
        for (int k = t; k < 18;  k += 256) wp[WP_W3 + k] = wf3[k];
        for (int k = t; k < 3;   k += 256) wp[WP_B3 + k] = bf3[k];
        for (int k = t; k < 162; k += 256) wp[WP_SOLID + WP_W1 + k] = sw1[k];
        for (int k = t; k < 9;   k += 256) wp[WP_SOLID + WP_B1 + k] = sb1[k];
        for (int k = t; k < 54;  k += 256) wp[WP_SOLID + WP_W2 + k] = sw2[k];
        for (int k = t; k < 6;   k += 256) wp[WP_SOLID + WP_B2 + k] = sb2[k];
        for (int k = t; k < 18;  k += 256) wp[WP_SOLID + WP_W3 + k] = sw3[k];
        for (int k = t; k < 3;   k += 256) wp[WP_SOLID + WP_B3 + k] = sb3[k];
    }
}

__global__ __launch_bounds__(256)
void compact_kernel(const int* __restrict__ mask,
                    const float* __restrict__ data,
                    float* __restrict__ wsp) {
    const int lane = threadIdx.x & 63;
    const int n = blockIdx.x * 4 + (threadIdx.x >> 6);
    int* counts_f = (int*)(wsp + OFF_CF);
    int* counts_s = (int*)(wsp + OFF_CS);
    unsigned short* lf = (unsigned short*)(wsp + OFF_LISTS) + (size_t)n * MCOLS;
    unsigned short* ls = lf + LF_CAP;
    const int* mrow = mask + (size_t)n * MCOLS;
    int bf = 0, bs = 0;
    const unsigned long long ltmask = (1ull << lane) - 1ull;
#pragma unroll 1
    for (int it = 0; it < MCOLS / 64; ++it) {
        const int m = it * 64 + lane;
        const int mk = mrow[m];
        const float flag = data[m * 7 + 6];
        const bool af = mk && (flag > 0.f);
        const bool as = mk && (flag < 1.f);
        const unsigned long long balf = __ballot(af);
        const unsigned long long bals = __ballot(as);
        if (af) lf[bf + __popcll(balf & ltmask)] = (unsigned short)m;
        if (as) ls[bs + __popcll(bals & ltmask)] = (unsigned short)m;
        bf += __popcll(balf);
        bs += __popcll(bals);
    }
    if (lane == 0) { counts_f[n] = bf; counts_s[n] = bs; }
}

// Champion (R11 winner), single kernel — no A/B scaffolding this round.
__global__ __launch_bounds__(256, 4)
void main_ilp(const float* __restrict__ wsp, float* __restrict__ out) {
    const int n = blockIdx.x;
    const int tid = threadIdx.x;
    __shared__ float red[3][4];
    const float* __restrict__ W  = wsp + OFF_WP;
    const float* __restrict__ Bf = wsp + OFF_BF + n * 20;
    const float* __restrict__ Bs = wsp + OFF_BS + n * 20;
    const int cf = ((const int*)(wsp + OFF_CF))[n];
    const int cs = ((const int*)(wsp + OFF_CS))[n];
    const unsigned short* lf = (const unsigned short*)(wsp + OFF_LISTS) + (size_t)n * MCOLS;
    const unsigned short* ls = lf + LF_CAP;

    float p0 = 0.f, p1 = 0.f, p2 = 0.f;
    row_loop_ilp(wsp + OFF_AF, lf, cf, Bf, W, tid, p0, p1, p2);
    row_loop_ilp(wsp + OFF_AS, ls, cs, Bs, W + WP_SOLID, tid, p0, p1, p2);

#pragma unroll
    for (int off = 32; off > 0; off >>= 1) {
        p0 += __shfl_xor(p0, off, 64);
        p1 += __shfl_xor(p1, off, 64);
        p2 += __shfl_xor(p2, off, 64);
    }
    const int wid = tid >> 6;
    if ((tid & 63) == 0) { red[0][wid] = p0; red[1][wid] = p1; red[2][wid] = p2; }
    __syncthreads();
    if (tid == 0) {
        float a0 = 0.f, a1 = 0.f, a2 = 0.f;
#pragma unroll
        for (int w = 0; w < 4; ++w) { a0 += red[0][w]; a1 += red[1][w]; a2 += red[2][w]; }
        out[n * 3 + 0] = a0; out[n * 3 + 1] = a1; out[n * 3 + 2] = a2;
    }
}

extern "C" void kernel_launch(void* const* d_in, const int* in_sizes, int n_in,
                              void* d_out, int out_size, void* d_ws, size_t ws_size,
                              hipStream_t stream) {
    const int*   mask  = (const int*)d_in[0];
    const int*   index = (const int*)d_in[1];
    const float* data  = (const float*)d_in[2];
    const float* wf0   = (const float*)d_in[3];
    const float* bf0   = (const float*)d_in[4];
    const float* wf1   = (const float*)d_in[5];
    const float* bf1   = (const float*)d_in[6];
    const float* wf2   = (const float*)d_in[7];
    const float* bf2   = (const float*)d_in[8];
    const float* wf3   = (const float*)d_in[9];
    const float* bf3   = (const float*)d_in[10];
    const float* sw0   = (const float*)d_in[11];
    const float* sb0   = (const float*)d_in[12];
    const float* sw1   = (const float*)d_in[13];
    const float* sb1   = (const float*)d_in[14];
    const float* sw2   = (const float*)d_in[15];
    const float* sb2   = (const float*)d_in[16];
    const float* sw3   = (const float*)d_in[17];
    const float* sb3   = (const float*)d_in[18];
    float* wsp = (float*)d_ws;
    float* out = (float*)d_out;

    prep_kernel<<<dim3(8), dim3(256), 0, stream>>>(
        index, data, wf0, bf0, sw0, sb0, wf1, bf1, wf2, bf2, wf3, bf3,
        sw1, sb1, sw2, sb2, sw3, sb3, wsp);
    compact_kernel<<<dim3(NROWS / 4), dim3(256), 0, stream>>>(mask, data, wsp);
    main_ilp<<<dim3(NROWS), dim3(256), 0, stream>>>(wsp, out);
}